// Round 10
// baseline (763.595 us; speedup 1.0000x reference)
//
#include <hip/hip_runtime.h>
#include <math.h>

#define CDIM 256
#define HD 8
#define DD 32
#define NT 3
#define ET 5
#define QWC (ET * CDIM)     // 1280
#define BCOLS 1792          // k(256) | v(256) | qw(1280)

typedef unsigned short u16;
typedef __attribute__((ext_vector_type(8))) short s16x8;
typedef __attribute__((ext_vector_type(4))) float f32x4;

__device__ __forceinline__ float b2f(u16 u) { return __uint_as_float(((unsigned)u) << 16); }
__device__ __forceinline__ u16 f2b(float x) {
    unsigned u = __float_as_uint(x);
    return (u16)((u + 0x7FFF + ((u >> 16) & 1)) >> 16);
}

// ================= node-type buckets (atomic-free, stable) =================
__global__ void bhist_k(const int* __restrict__ ntype, int N, int nblk, int* __restrict__ bcnt) {
    __shared__ int wc[4][NT];
    int b = blockIdx.x, tid = threadIdx.x, lane = tid & 63, w = tid >> 6;
    int i = b * 256 + tid;
    int t = (i < N) ? ntype[i] : -1;
#pragma unroll
    for (int r = 0; r < NT; ++r) {
        unsigned long long m = __ballot(t == r);
        if (lane == 0) wc[w][r] = __popcll(m);
    }
    __syncthreads();
    if (tid < NT) bcnt[tid * nblk + b] = wc[0][tid] + wc[1][tid] + wc[2][tid] + wc[3][tid];
}

__global__ void bscan_k(const int* __restrict__ bcnt, int* __restrict__ base,
                        int* __restrict__ off, int total, int nblk, int N) {
    __shared__ int s[1024];
    int t = threadIdx.x;
    int v = (t < total) ? bcnt[t] : 0;
    s[t] = v; __syncthreads();
    for (int o = 1; o < 1024; o <<= 1) {
        int u = (t >= o) ? s[t - o] : 0; __syncthreads();
        s[t] += u; __syncthreads();
    }
    if (t < total) base[t] = s[t] - v;
    if (t < NT) off[t] = s[t * nblk] - bcnt[t * nblk];
    if (t == NT) off[NT] = N;
}

__global__ void bscatter_k(const int* __restrict__ ntype, int N, int nblk,
                           const int* __restrict__ base, int* __restrict__ perm) {
    __shared__ int wc[4][NT];
    __shared__ int woff[4][NT];
    int b = blockIdx.x, tid = threadIdx.x, lane = tid & 63, w = tid >> 6;
    int i = b * 256 + tid;
    int t = (i < N) ? ntype[i] : -1;
    unsigned long long mlt = (1ULL << lane) - 1;
    int rank = 0;
#pragma unroll
    for (int r = 0; r < NT; ++r) {
        unsigned long long m = __ballot(t == r);
        if (lane == 0) wc[w][r] = __popcll(m);
        if (t == r) rank = __popcll(m & mlt);
    }
    __syncthreads();
    if (tid == 0) {
#pragma unroll
        for (int r = 0; r < NT; ++r) {
            int a = 0;
#pragma unroll
            for (int w0 = 0; w0 < 4; ++w0) { woff[w0][r] = a; a += wc[w0][r]; }
        }
    }
    __syncthreads();
    if (t >= 0) perm[base[t * nblk + b] + woff[w][t] + rank] = i;
}

// ================= edge counting sort by key = dst*ET + etype =================
__global__ void ehist_k(const int* __restrict__ dst, const int* __restrict__ etype, int E,
                        int* __restrict__ khist) {
    int i = blockIdx.x * 256 + threadIdx.x;
    if (i < E) atomicAdd(&khist[dst[i] * ET + etype[i]], 1);
}

__global__ void kscan1_k(const int* __restrict__ khist, int* __restrict__ kscan,
                         int* __restrict__ bsum, int KEYS) {
    __shared__ int s[256];
    int b = blockIdx.x, t = threadIdx.x, i = b * 256 + t;
    int v = (i < KEYS) ? khist[i] : 0;
    s[t] = v; __syncthreads();
    for (int o = 1; o < 256; o <<= 1) {
        int u = (t >= o) ? s[t - o] : 0; __syncthreads();
        s[t] += u; __syncthreads();
    }
    if (i < KEYS) kscan[i] = s[t] - v;
    if (t == 255) bsum[b] = s[t];
}

__global__ void kscan2_k(int* __restrict__ bsum, int NB) {
    __shared__ int s[1024];
    int t = threadIdx.x;
    int v = (t < NB) ? bsum[t] : 0;
    s[t] = v; __syncthreads();
    for (int o = 1; o < 1024; o <<= 1) {
        int u = (t >= o) ? s[t - o] : 0; __syncthreads();
        s[t] += u; __syncthreads();
    }
    if (t < NB) bsum[t] = s[t] - v;
}

__global__ void kscan3_k(int* __restrict__ kscan, const int* __restrict__ bsum, int KEYS) {
    int i = blockIdx.x * 256 + threadIdx.x;
    if (i < KEYS) kscan[i] += bsum[blockIdx.x];
}

__global__ void rowptr_k(const int* __restrict__ kscan, int* __restrict__ rowptr, int KEYS, int E) {
    int i = blockIdx.x * 256 + threadIdx.x;
    if (i < KEYS) rowptr[i] = kscan[i];
    if (i == KEYS) rowptr[KEYS] = E;
}

__global__ void escatter_k(const int* __restrict__ src, const int* __restrict__ dst,
                           const int* __restrict__ etype, int E,
                           int* __restrict__ kscan, int* __restrict__ epay) {
    int e = blockIdx.x * 256 + threadIdx.x;
    if (e < E) {
        int pos = atomicAdd(&kscan[dst[e] * ET + etype[e]], 1);
        epay[pos] = src[e];
    }
}

// ================= W[t][k][c] f32 -> BigB[t][colbase+c][k] bf16 =================
__global__ __launch_bounds__(256) void wconv_k(const float* __restrict__ W, u16* __restrict__ Big,
                                               int colbase) {
    __shared__ u16 s[64][72];
    int k0 = blockIdx.x * 64, c0 = blockIdx.y * 64, t = blockIdx.z;
    const float* Wp = W + (size_t)t * CDIM * CDIM;
    int r = threadIdx.x >> 2, q = (threadIdx.x & 3) * 16;
#pragma unroll
    for (int m = 0; m < 16; m += 4) {
        float4 v = *(const float4*)(Wp + (size_t)(k0 + r) * CDIM + c0 + q + m);
        s[r][q + m + 0] = f2b(v.x); s[r][q + m + 1] = f2b(v.y);
        s[r][q + m + 2] = f2b(v.z); s[r][q + m + 3] = f2b(v.w);
    }
    __syncthreads();
    int c = threadIdx.x >> 2, kq = (threadIdx.x & 3) * 16;
    u16* op = Big + ((size_t)t * BCOLS + colbase + c0 + c) * CDIM + k0 + kq;
#pragma unroll
    for (int m = 0; m < 16; m += 4) {
        ushort4 o;
        o.x = s[kq + m + 0][c]; o.y = s[kq + m + 1][c];
        o.z = s[kq + m + 2][c]; o.w = s[kq + m + 3][c];
        *(ushort4*)(op + m) = o;
    }
}

// ===== fold Ratt into Wq: BigB[t][512 + et*256+h*32+m][c] = sum_f Wq[t][c][h32+f]*Ratt[et,h,m,f]
__global__ __launch_bounds__(256) void qfold_k(const float* __restrict__ Wq,
                                               const float* __restrict__ Ratt,
                                               u16* __restrict__ Big) {
    __shared__ float Ra[DD][DD];   // [m][f]
    int b = blockIdx.x;            // t*(ET*HD) + et*HD + h
    int t = b / (ET * HD);
    int eh = b % (ET * HD);
    int et = eh >> 3, h = eh & 7;
    int tid = threadIdx.x;

    ((float4*)&Ra[0][0])[tid] = ((const float4*)(Ratt + (size_t)eh * (DD * DD)))[tid];
    __syncthreads();

    int c = tid;
    const float* wr = Wq + (size_t)t * (CDIM * CDIM) + (size_t)c * CDIM + h * DD;
    float wrow[DD];
#pragma unroll
    for (int f = 0; f < DD; f += 4) {
        float4 v = *(const float4*)(wr + f);
        wrow[f] = v.x; wrow[f + 1] = v.y; wrow[f + 2] = v.z; wrow[f + 3] = v.w;
    }
    for (int m = 0; m < DD; ++m) {
        float acc = 0.f;
#pragma unroll
        for (int f = 0; f < DD; ++f) acc += wrow[f] * Ra[m][f];
        Big[((size_t)t * BCOLS + 512 + et * 256 + h * 32 + m) * CDIM + c] = f2b(acc);
    }
}

// ===== fold Rmsg into Wa: af_b[t][col][et*256+h*32+f] = sum_m Rmsg[et,h,f,m]*Wa[t][h32+m][col]
__global__ __launch_bounds__(256) void afold_k(const float* __restrict__ Wa,
                                               const float* __restrict__ Rmsg,
                                               u16* __restrict__ af_b) {
    __shared__ float Rm[DD][DD];   // [f][m]
    int b = blockIdx.x;
    int t = b / (ET * HD);
    int eh = b % (ET * HD);
    int et = eh >> 3, h = eh & 7;
    int tid = threadIdx.x;

    ((float4*)&Rm[0][0])[tid] = ((const float4*)(Rmsg + (size_t)eh * (DD * DD)))[tid];
    __syncthreads();

    int col = tid;
    float wcol[DD];
#pragma unroll
    for (int m = 0; m < DD; ++m)
        wcol[m] = Wa[(size_t)t * (CDIM * CDIM) + (size_t)(h * 32 + m) * CDIM + col];

    u16* op = af_b + ((size_t)t * CDIM + col) * QWC + et * 256 + h * 32;
    for (int f = 0; f < DD; ++f) {
        float acc = 0.f;
#pragma unroll
        for (int m = 0; m < DD; ++m) acc += Rm[f][m] * wcol[m];
        op[f] = f2b(acc);
    }
}

// ================= mega GEMM: [k|v|qw] = x @ BigB =================
// A fragments loaded directly from x (per-lane, f32->bf16 in regs, one time);
// per col-tile: B staged via regs->LDS, 32 MFMA, output staged via LDS -> coalesced 16B stores.
__global__ __launch_bounds__(256) void megagemm_k(
    const float* __restrict__ x, const u16* __restrict__ BigB,
    u16* __restrict__ kb, u16* __restrict__ vb, u16* __restrict__ qwsv,
    const int* __restrict__ perm, const int* __restrict__ off, int N, int bpt)
{
    __shared__ u16 Bs[64][268];      // 34.3 KB
    __shared__ u16 Os[64][68];       // 8.7 KB
    __shared__ int ridx[64];

    int t = blockIdx.x / bpt, bi = blockIdx.x % bpt;
    int i0 = off[t] + bi * 64, iend = off[t + 1];
    if (i0 >= iend) return;
    int tid = threadIdx.x;
    if (tid < 64) ridx[tid] = (i0 + tid < iend) ? perm[i0 + tid] : -1;
    __syncthreads();

    int lane = tid & 63, wid = tid >> 6;
    int wr = wid >> 1, wc = wid & 1;
    int l15 = lane & 15, lk = (lane >> 4) * 8;
    int sr = tid >> 2, sq = (tid & 3) * 8;

    // ---- A fragments direct from x, f32 -> bf16, persistent in regs ----
    s16x8 afr0[8], afr1[8];
    {
        int rA = wr * 32 + l15, rB = rA + 16;
        int nA = ridx[rA], nB = ridx[rB];
        const float* pA = x + (size_t)(nA < 0 ? 0 : nA) * CDIM + lk;
        const float* pB = x + (size_t)(nB < 0 ? 0 : nB) * CDIM + lk;
#pragma unroll
        for (int kc = 0; kc < 8; ++kc) {
            s16x8 fa = (s16x8)0, fb = (s16x8)0;
            if (nA >= 0) {
                float4 u0 = *(const float4*)(pA + kc * 32);
                float4 u1 = *(const float4*)(pA + kc * 32 + 4);
                fa[0] = (short)f2b(u0.x); fa[1] = (short)f2b(u0.y);
                fa[2] = (short)f2b(u0.z); fa[3] = (short)f2b(u0.w);
                fa[4] = (short)f2b(u1.x); fa[5] = (short)f2b(u1.y);
                fa[6] = (short)f2b(u1.z); fa[7] = (short)f2b(u1.w);
            }
            if (nB >= 0) {
                float4 u0 = *(const float4*)(pB + kc * 32);
                float4 u1 = *(const float4*)(pB + kc * 32 + 4);
                fb[0] = (short)f2b(u0.x); fb[1] = (short)f2b(u0.y);
                fb[2] = (short)f2b(u0.z); fb[3] = (short)f2b(u0.w);
                fb[4] = (short)f2b(u1.x); fb[5] = (short)f2b(u1.y);
                fb[6] = (short)f2b(u1.z); fb[7] = (short)f2b(u1.w);
            }
            afr0[kc] = fa;
            afr1[kc] = fb;
        }
    }

    const u16* bbase = BigB + (size_t)t * BCOLS * CDIM;
    uint4 bpre[8];
#pragma unroll
    for (int kc = 0; kc < 8; ++kc)
        bpre[kc] = *(const uint4*)(bbase + (size_t)sr * CDIM + kc * 32 + sq);

    int rbase = wr * 32 + (lane >> 4) * 4;
    int orow = tid >> 2, ocq = (tid & 3) * 16;

    for (int y = 0; y < 28; ++y) {
        __syncthreads();                  // prev Bs reads + prev Os reads done
#pragma unroll
        for (int kc = 0; kc < 8; ++kc)
            *(uint4*)&Bs[sr][kc * 32 + sq] = bpre[kc];
        __syncthreads();
        if (y + 1 < 28) {
            const u16* bn = bbase + (size_t)((y + 1) * 64 + sr) * CDIM;
#pragma unroll
            for (int kc = 0; kc < 8; ++kc)
                bpre[kc] = *(const uint4*)(bn + kc * 32 + sq);
        }

        f32x4 a00 = {0.f,0.f,0.f,0.f}, a01 = {0.f,0.f,0.f,0.f};
        f32x4 a10 = {0.f,0.f,0.f,0.f}, a11 = {0.f,0.f,0.f,0.f};
#pragma unroll
        for (int kc = 0; kc < 8; ++kc) {
            s16x8 bf0 = *(const s16x8*)&Bs[wc * 32 + l15][kc * 32 + lk];
            s16x8 bf1 = *(const s16x8*)&Bs[wc * 32 + 16 + l15][kc * 32 + lk];
            a00 = __builtin_amdgcn_mfma_f32_16x16x32_bf16(afr0[kc], bf0, a00, 0, 0, 0);
            a01 = __builtin_amdgcn_mfma_f32_16x16x32_bf16(afr0[kc], bf1, a01, 0, 0, 0);
            a10 = __builtin_amdgcn_mfma_f32_16x16x32_bf16(afr1[kc], bf0, a10, 0, 0, 0);
            a11 = __builtin_amdgcn_mfma_f32_16x16x32_bf16(afr1[kc], bf1, a11, 0, 0, 0);
        }

        // stage 64x64 output tile in LDS
#pragma unroll
        for (int mi = 0; mi < 2; ++mi) {
#pragma unroll
            for (int r = 0; r < 4; ++r) {
                int row = rbase + mi * 16 + r;
                Os[row][wc * 32 + l15]      = f2b(mi == 0 ? a00[r] : a10[r]);
                Os[row][wc * 32 + 16 + l15] = f2b(mi == 0 ? a01[r] : a11[r]);
            }
        }
        __syncthreads();

        // coalesced 2x16B stores per thread (full 128B lines per row)
        int node = ridx[orow];
        if (node >= 0) {
            u16* outp; int ostr, oc0;
            if (y < 4)      { outp = kb;   ostr = CDIM; oc0 = y * 64; }
            else if (y < 8) { outp = vb;   ostr = CDIM; oc0 = (y - 4) * 64; }
            else            { outp = qwsv; ostr = QWC;  oc0 = (y - 8) * 64; }
            uint2 w0 = *(const uint2*)&Os[orow][ocq];
            uint2 w1 = *(const uint2*)&Os[orow][ocq + 4];
            uint2 w2 = *(const uint2*)&Os[orow][ocq + 8];
            uint2 w3 = *(const uint2*)&Os[orow][ocq + 12];
            u16* gp = outp + (size_t)node * ostr + oc0 + ocq;
            *(uint4*)gp       = make_uint4(w0.x, w0.y, w1.x, w1.y);
            *(uint4*)(gp + 8) = make_uint4(w2.x, w2.y, w3.x, w3.y);
        }
    }
}

// ================= out GEMM: out = svn @ af_b (K=1280), 4 col-tiles in regs =================
__global__ __launch_bounds__(256) void outgemm_k(
    const u16* __restrict__ svn, const u16* __restrict__ af_b, float* __restrict__ out,
    const int* __restrict__ perm, const int* __restrict__ off, int N, int bpt,
    const float* __restrict__ x, const float* __restrict__ skip)
{
    __shared__ u16 As[64][36];
    __shared__ u16 Bs[4][64][36];
    __shared__ int ridx[64];

    int t = blockIdx.x / bpt, bi = blockIdx.x % bpt;
    int i0 = off[t] + bi * 64, iend = off[t + 1];
    if (i0 >= iend) return;
    int tid = threadIdx.x;
    if (tid < 64) ridx[tid] = (i0 + tid < iend) ? perm[i0 + tid] : -1;
    __syncthreads();

    int sr = tid >> 2, sq = (tid & 3) * 8;
    int ar = ridx[sr];
    const u16* asrc = svn + (size_t)(ar < 0 ? 0 : ar) * QWC + sq;
    const u16* bbase = af_b + (size_t)t * CDIM * QWC;

    int lane = tid & 63, wid = tid >> 6;
    int wr = wid >> 1, wc = wid & 1;
    int l15 = lane & 15, lk = (lane >> 4) * 8;

    f32x4 acc[4][2][2];
#pragma unroll
    for (int y = 0; y < 4; ++y)
#pragma unroll
        for (int mi = 0; mi < 2; ++mi)
#pragma unroll
            for (int ci = 0; ci < 2; ++ci)
                acc[y][mi][ci] = (f32x4){0.f, 0.f, 0.f, 0.f};

    uint4 apre = make_uint4(0, 0, 0, 0), bpre[4];
    if (ar >= 0) apre = *(const uint4*)(asrc);
#pragma unroll
    for (int y = 0; y < 4; ++y)
        bpre[y] = *(const uint4*)(bbase + (size_t)(y * 64 + sr) * QWC + sq);

    for (int kc = 0; kc < 40; ++kc) {
        __syncthreads();
        *(uint4*)&As[sr][sq] = apre;
#pragma unroll
        for (int y = 0; y < 4; ++y)
            *(uint4*)&Bs[y][sr][sq] = bpre[y];
        __syncthreads();

        if (kc + 1 < 40) {
            int ko = (kc + 1) * 32;
            if (ar >= 0) apre = *(const uint4*)(asrc + ko);
#pragma unroll
            for (int y = 0; y < 4; ++y)
                bpre[y] = *(const uint4*)(bbase + (size_t)(y * 64 + sr) * QWC + ko + sq);
        }

        s16x8 af0 = *(const s16x8*)&As[wr * 32 + l15][lk];
        s16x8 af1 = *(const s16x8*)&As[wr * 32 + 16 + l15][lk];
#pragma unroll
        for (int y = 0; y < 4; ++y) {
            s16x8 bf0 = *(const s16x8*)&Bs[y][wc * 32 + l15][lk];
            s16x8 bf1 = *(const s16x8*)&Bs[y][wc * 32 + 16 + l15][lk];
            acc[y][0][0] = __builtin_amdgcn_mfma_f32_16x16x32_bf16(af0, bf0, acc[y][0][0], 0, 0, 0);
            acc[y][0][1] = __builtin_amdgcn_mfma_f32_16x16x32_bf16(af0, bf1, acc[y][0][1], 0, 0, 0);
            acc[y][1][0] = __builtin_amdgcn_mfma_f32_16x16x32_bf16(af1, bf0, acc[y][1][0], 0, 0, 0);
            acc[y][1][1] = __builtin_amdgcn_mfma_f32_16x16x32_bf16(af1, bf1, acc[y][1][1], 0, 0, 0);
        }
    }

    float alpha = 1.f / (1.f + __expf(-skip[t]));
    float beta = 1.f - alpha;
    int rbase = wr * 32 + (lane >> 4) * 4;
#pragma unroll
    for (int y = 0; y < 4; ++y) {
        int c0i = y * 64 + wc * 32 + l15;
#pragma unroll
        for (int mi = 0; mi < 2; ++mi) {
#pragma unroll
            for (int r = 0; r < 4; ++r) {
                int node = ridx[rbase + mi * 16 + r];
                if (node < 0) continue;
                size_t b0 = (size_t)node * CDIM + c0i;
                out[b0]      = acc[y][mi][0][r] * alpha + x[b0] * beta;
                out[b0 + 16] = acc[y][mi][1][r] * alpha + x[b0 + 16] * beta;
            }
        }
    }
}

// ================= gather: one wave per dst; Sv in regs across ets; svn in-place =========
__global__ __launch_bounds__(256) void gather2_k(
    const u16* __restrict__ kb, const u16* __restrict__ vb, u16* __restrict__ qwsv,
    const float* __restrict__ pri, const int* __restrict__ rowptr, const int* __restrict__ epay,
    int N)
{
    int d = (blockIdx.x * 256 + threadIdx.x) >> 6;
    if (d >= N) return;
    int lane = threadIdx.x & 63, h = lane >> 3;
    const float rsD = 0.17677669529663687f;
    float dsum = 0.f;
    size_t rowb = (size_t)d * QWC + lane * 4;

    float Sv[ET][4];
#pragma unroll
    for (int et = 0; et < ET; ++et) { Sv[et][0] = Sv[et][1] = Sv[et][2] = Sv[et][3] = 0.f; }

#pragma unroll
    for (int et = 0; et < ET; ++et) {
        int key = d * ET + et;
        int p0 = rowptr[key], p1 = rowptr[key + 1];
        if (p0 >= p1) continue;
        float prif = pri[et * HD + h] * rsD;
        ushort4 qu = *(const ushort4*)(qwsv + rowb + et * 256);
        float q0 = b2f(qu.x), q1 = b2f(qu.y), q2 = b2f(qu.z), q3 = b2f(qu.w);
        for (int p = p0; p < p1; ++p) {
            int s = epay[p];
            ushort4 ku = *(const ushort4*)(kb + (size_t)s * CDIM + lane * 4);
            float tt = b2f(ku.x) * q0 + b2f(ku.y) * q1 + b2f(ku.z) * q2 + b2f(ku.w) * q3;
            tt += __shfl_xor(tt, 1, 8);
            tt += __shfl_xor(tt, 2, 8);
            tt += __shfl_xor(tt, 4, 8);
            float ex = __expf(tt * prif);
            ushort4 vu = *(const ushort4*)(vb + (size_t)s * CDIM + lane * 4);
            Sv[et][0] += ex * b2f(vu.x); Sv[et][1] += ex * b2f(vu.y);
            Sv[et][2] += ex * b2f(vu.z); Sv[et][3] += ex * b2f(vu.w);
            dsum += ex;
        }
    }

    float inv = dsum > 0.f ? 1.f / dsum : 0.f;
#pragma unroll
    for (int et = 0; et < ET; ++et) {
        ushort4 o;
        o.x = f2b(Sv[et][0] * inv); o.y = f2b(Sv[et][1] * inv);
        o.z = f2b(Sv[et][2] * inv); o.w = f2b(Sv[et][3] * inv);
        *(ushort4*)(qwsv + rowb + et * 256) = o;
    }
}

// ================= launch =================
extern "C" void kernel_launch(void* const* d_in, const int* in_sizes, int n_in,
                              void* d_out, int out_size, void* d_ws, size_t ws_size,
                              hipStream_t stream) {
    const float* x    = (const float*)d_in[0];
    const float* Wk   = (const float*)d_in[1];
    const float* Wq   = (const float*)d_in[2];
    const float* Wv   = (const float*)d_in[3];
    const float* Ratt = (const float*)d_in[4];
    const float* Rmsg = (const float*)d_in[5];
    const float* pri  = (const float*)d_in[6];
    const float* Wa   = (const float*)d_in[7];
    const float* skip = (const float*)d_in[8];
    const int* src   = (const int*)d_in[9];
    const int* dst   = (const int*)d_in[10];
    const int* etype = (const int*)d_in[11];
    const int* ntype = (const int*)d_in[12];

    int N = in_sizes[12];
    int E = in_sizes[9];
    const size_t NC = (size_t)N * CDIM;
    const int KEYS = N * ET;
    const int NB = (KEYS + 255) / 256;
    const int nblk = (N + 255) / 256;
    const size_t BIGE = (size_t)NT * BCOLS * CDIM;     // mega B (u16 elems)
    const size_t AFE  = (size_t)NT * CDIM * QWC;       // folded out-B (u16 elems)

    // ---- workspace (~186 MB) ----
    u16* kb   = (u16*)d_ws;                  // NC
    u16* vb   = kb + NC;                     // NC
    u16* qwsv = vb + NC;                     // 5*NC (qw then svn, in-place)
    u16* BigB = qwsv + 5 * NC;               // BIGE
    u16* af_b = BigB + BIGE;                 // AFE
    int* rowptr = (int*)(af_b + AFE);        // KEYS+1  (persistent)
    int* perm   = rowptr + KEYS + 1;         // N       (persistent)
    int* epay   = perm + N;                  // E       (persistent)
    int* off    = epay + E;                  // NT+1    (persistent)
    // setup-only ints aliased into qwsv (dead before megagemm writes it)
    int* khist = (int*)qwsv;                 // KEYS (zeroed)
    int* kscan = khist + KEYS;               // KEYS
    int* bsum  = kscan + KEYS;               // 1024
    int* bcnt  = bsum + 1024;                // NT*nblk
    int* base  = bcnt + NT * nblk;           // NT*nblk

    hipMemsetAsync(khist, 0, (size_t)KEYS * sizeof(int), stream);

    // node buckets (atomic-free, stable)
    bhist_k<<<nblk, 256, 0, stream>>>(ntype, N, nblk, bcnt);
    bscan_k<<<1, 1024, 0, stream>>>(bcnt, base, off, NT * nblk, nblk, N);
    bscatter_k<<<nblk, 256, 0, stream>>>(ntype, N, nblk, base, perm);

    // edge counting sort by (dst, etype) -> CSR
    ehist_k<<<(E + 255) / 256, 256, 0, stream>>>(dst, etype, E, khist);
    kscan1_k<<<NB, 256, 0, stream>>>(khist, kscan, bsum, KEYS);
    kscan2_k<<<1, 1024, 0, stream>>>(bsum, NB);
    kscan3_k<<<NB, 256, 0, stream>>>(kscan, bsum, KEYS);
    rowptr_k<<<(KEYS + 256) / 256, 256, 0, stream>>>(kscan, rowptr, KEYS, E);
    escatter_k<<<(E + 255) / 256, 256, 0, stream>>>(src, dst, etype, E, kscan, epay);

    // B prep: Wk (cols 0-255), Wv (cols 256-511), folded Wq*Ratt (cols 512-1791), Rmsg*Wa
    dim3 wg(4, 4, NT);
    wconv_k<<<wg, 256, 0, stream>>>(Wk, BigB, 0);
    wconv_k<<<wg, 256, 0, stream>>>(Wv, BigB, 256);
    qfold_k<<<NT * ET * HD, 256, 0, stream>>>(Wq, Ratt, BigB);
    afold_k<<<NT * ET * HD, 256, 0, stream>>>(Wa, Rmsg, af_b);

    int bpt = (N + 63) / 64;

    // fused k|v|qw GEMM (A frags direct-from-global, LDS-staged coalesced stores)
    megagemm_k<<<NT * bpt, 256, 0, stream>>>(x, BigB, kb, vb, qwsv, perm, off, N, bpt);

    // edge gather: svn (attn-weighted, den-normalized v-sums) in-place over qw
    gather2_k<<<(N * 64 + 255) / 256, 256, 0, stream>>>(kb, vb, qwsv, pri, rowptr, epay, N);

    // out = svn @ (Rmsg*Wa) with sigmoid-gated skip (K = 1280, A read once)
    outgemm_k<<<NT * bpt, 256, 0, stream>>>(qwsv, af_b, (float*)d_out, perm, off, N, bpt,
                                            x, skip);
}

// Round 11
// 610.571 us; speedup vs baseline: 1.2506x; 1.2506x over previous
//
#include <hip/hip_runtime.h>
#include <math.h>

#define CDIM 256
#define HD 8
#define DD 32
#define NT 3
#define ET 5
#define QWC (ET * CDIM)     // 1280

typedef unsigned short u16;
typedef __attribute__((ext_vector_type(8))) short s16x8;
typedef __attribute__((ext_vector_type(4))) float f32x4;

__device__ __forceinline__ float b2f(u16 u) { return __uint_as_float(((unsigned)u) << 16); }
__device__ __forceinline__ u16 f2b(float x) {
    unsigned u = __float_as_uint(x);
    return (u16)((u + 0x7FFF + ((u >> 16) & 1)) >> 16);
}

// ================= node-type buckets (atomic-free, stable) =================
__global__ void bhist_k(const int* __restrict__ ntype, int N, int nblk, int* __restrict__ bcnt) {
    __shared__ int wc[4][NT];
    int b = blockIdx.x, tid = threadIdx.x, lane = tid & 63, w = tid >> 6;
    int i = b * 256 + tid;
    int t = (i < N) ? ntype[i] : -1;
#pragma unroll
    for (int r = 0; r < NT; ++r) {
        unsigned long long m = __ballot(t == r);
        if (lane == 0) wc[w][r] = __popcll(m);
    }
    __syncthreads();
    if (tid < NT) bcnt[tid * nblk + b] = wc[0][tid] + wc[1][tid] + wc[2][tid] + wc[3][tid];
}

__global__ void bscan_k(const int* __restrict__ bcnt, int* __restrict__ base,
                        int* __restrict__ off, int total, int nblk, int N) {
    __shared__ int s[1024];
    int t = threadIdx.x;
    int v = (t < total) ? bcnt[t] : 0;
    s[t] = v; __syncthreads();
    for (int o = 1; o < 1024; o <<= 1) {
        int u = (t >= o) ? s[t - o] : 0; __syncthreads();
        s[t] += u; __syncthreads();
    }
    if (t < total) base[t] = s[t] - v;
    if (t < NT) off[t] = s[t * nblk] - bcnt[t * nblk];
    if (t == NT) off[NT] = N;
}

__global__ void bscatter_k(const int* __restrict__ ntype, int N, int nblk,
                           const int* __restrict__ base, int* __restrict__ perm) {
    __shared__ int wc[4][NT];
    __shared__ int woff[4][NT];
    int b = blockIdx.x, tid = threadIdx.x, lane = tid & 63, w = tid >> 6;
    int i = b * 256 + tid;
    int t = (i < N) ? ntype[i] : -1;
    unsigned long long mlt = (1ULL << lane) - 1;
    int rank = 0;
#pragma unroll
    for (int r = 0; r < NT; ++r) {
        unsigned long long m = __ballot(t == r);
        if (lane == 0) wc[w][r] = __popcll(m);
        if (t == r) rank = __popcll(m & mlt);
    }
    __syncthreads();
    if (tid == 0) {
#pragma unroll
        for (int r = 0; r < NT; ++r) {
            int a = 0;
#pragma unroll
            for (int w0 = 0; w0 < 4; ++w0) { woff[w0][r] = a; a += wc[w0][r]; }
        }
    }
    __syncthreads();
    if (t >= 0) perm[base[t * nblk + b] + woff[w][t] + rank] = i;
}

// ================= edge counting sort by key = dst*ET + etype =================
__global__ void ehist_k(const int* __restrict__ dst, const int* __restrict__ etype, int E,
                        int* __restrict__ khist) {
    int i = blockIdx.x * 256 + threadIdx.x;
    if (i < E) atomicAdd(&khist[dst[i] * ET + etype[i]], 1);
}

__global__ void kscan1_k(const int* __restrict__ khist, int* __restrict__ kscan,
                         int* __restrict__ bsum, int KEYS) {
    __shared__ int s[256];
    int b = blockIdx.x, t = threadIdx.x, i = b * 256 + t;
    int v = (i < KEYS) ? khist[i] : 0;
    s[t] = v; __syncthreads();
    for (int o = 1; o < 256; o <<= 1) {
        int u = (t >= o) ? s[t - o] : 0; __syncthreads();
        s[t] += u; __syncthreads();
    }
    if (i < KEYS) kscan[i] = s[t] - v;
    if (t == 255) bsum[b] = s[t];
}

__global__ void kscan2_k(int* __restrict__ bsum, int NB) {
    __shared__ int s[1024];
    int t = threadIdx.x;
    int v = (t < NB) ? bsum[t] : 0;
    s[t] = v; __syncthreads();
    for (int o = 1; o < 1024; o <<= 1) {
        int u = (t >= o) ? s[t - o] : 0; __syncthreads();
        s[t] += u; __syncthreads();
    }
    if (t < NB) bsum[t] = s[t] - v;
}

__global__ void kscan3_k(int* __restrict__ kscan, const int* __restrict__ bsum, int KEYS) {
    int i = blockIdx.x * 256 + threadIdx.x;
    if (i < KEYS) kscan[i] += bsum[blockIdx.x];
}

__global__ void rowptr_k(const int* __restrict__ kscan, int* __restrict__ rowptr, int KEYS, int E) {
    int i = blockIdx.x * 256 + threadIdx.x;
    if (i < KEYS) rowptr[i] = kscan[i];
    if (i == KEYS) rowptr[KEYS] = E;
}

__global__ void escatter_k(const int* __restrict__ src, const int* __restrict__ dst,
                           const int* __restrict__ etype, int E,
                           int* __restrict__ kscan, int* __restrict__ epay) {
    int e = blockIdx.x * 256 + threadIdx.x;
    if (e < E) {
        int pos = atomicAdd(&kscan[dst[e] * ET + etype[e]], 1);
        epay[pos] = src[e];
    }
}

// ================= W[t][k][c] f32 -> Wtb[t][c][k] bf16 =================
__global__ __launch_bounds__(256) void wconv_k(const float* __restrict__ W, u16* __restrict__ Wtb) {
    __shared__ u16 s[64][72];
    int k0 = blockIdx.x * 64, c0 = blockIdx.y * 64, t = blockIdx.z;
    const float* Wp = W + (size_t)t * CDIM * CDIM;
    int r = threadIdx.x >> 2, q = (threadIdx.x & 3) * 16;
#pragma unroll
    for (int m = 0; m < 16; m += 4) {
        float4 v = *(const float4*)(Wp + (size_t)(k0 + r) * CDIM + c0 + q + m);
        s[r][q + m + 0] = f2b(v.x); s[r][q + m + 1] = f2b(v.y);
        s[r][q + m + 2] = f2b(v.z); s[r][q + m + 3] = f2b(v.w);
    }
    __syncthreads();
    int c = threadIdx.x >> 2, kq = (threadIdx.x & 3) * 16;
    u16* op = Wtb + ((size_t)t * CDIM + c0 + c) * CDIM + k0 + kq;
#pragma unroll
    for (int m = 0; m < 16; m += 4) {
        ushort4 o;
        o.x = s[kq + m + 0][c]; o.y = s[kq + m + 1][c];
        o.z = s[kq + m + 2][c]; o.w = s[kq + m + 3][c];
        *(ushort4*)(op + m) = o;
    }
}

// ===== fold Ratt into Wq: qf_b[t][et*256+h*32+m][c] = sum_f Wq[t][c][h32+f]*Ratt[et,h,m,f]
__global__ __launch_bounds__(256) void qfold_k(const float* __restrict__ Wq,
                                               const float* __restrict__ Ratt,
                                               u16* __restrict__ qf_b) {
    __shared__ float Ra[DD][DD];   // [m][f]
    int b = blockIdx.x;            // t*(ET*HD) + et*HD + h
    int t = b / (ET * HD);
    int eh = b % (ET * HD);
    int et = eh >> 3, h = eh & 7;
    int tid = threadIdx.x;

    ((float4*)&Ra[0][0])[tid] = ((const float4*)(Ratt + (size_t)eh * (DD * DD)))[tid];
    __syncthreads();

    int c = tid;
    const float* wr = Wq + (size_t)t * (CDIM * CDIM) + (size_t)c * CDIM + h * DD;
    float wrow[DD];
#pragma unroll
    for (int f = 0; f < DD; f += 4) {
        float4 v = *(const float4*)(wr + f);
        wrow[f] = v.x; wrow[f + 1] = v.y; wrow[f + 2] = v.z; wrow[f + 3] = v.w;
    }
    for (int m = 0; m < DD; ++m) {
        float acc = 0.f;
#pragma unroll
        for (int f = 0; f < DD; ++f) acc += wrow[f] * Ra[m][f];
        qf_b[((size_t)t * QWC + et * 256 + h * 32 + m) * CDIM + c] = f2b(acc);
    }
}

// ===== fold Rmsg into Wa: af_b[t][col][et*256+h*32+f] = sum_m Rmsg[et,h,f,m]*Wa[t][h32+m][col]
__global__ __launch_bounds__(256) void afold_k(const float* __restrict__ Wa,
                                               const float* __restrict__ Rmsg,
                                               u16* __restrict__ af_b) {
    __shared__ float Rm[DD][DD];   // [f][m]
    int b = blockIdx.x;
    int t = b / (ET * HD);
    int eh = b % (ET * HD);
    int et = eh >> 3, h = eh & 7;
    int tid = threadIdx.x;

    ((float4*)&Rm[0][0])[tid] = ((const float4*)(Rmsg + (size_t)eh * (DD * DD)))[tid];
    __syncthreads();

    int col = tid;
    float wcol[DD];
#pragma unroll
    for (int m = 0; m < DD; ++m)
        wcol[m] = Wa[(size_t)t * (CDIM * CDIM) + (size_t)(h * 32 + m) * CDIM + col];

    u16* op = af_b + ((size_t)t * CDIM + col) * QWC + et * 256 + h * 32;
    for (int f = 0; f < DD; ++f) {
        float acc = 0.f;
#pragma unroll
        for (int m = 0; m < DD; ++m) acc += Rm[f][m] * wcol[m];
        op[f] = f2b(acc);
    }
}

// ================= MFMA typed GEMM: out[perm[r]] = bf16( A[perm[r]] @ B[t] ) =================
// Grid: (bcols/64, NT*bpt) — col-tiles fastest so A-tile stays L2-hot across them.
__global__ __launch_bounds__(256) void gemm2_k(
    const float* __restrict__ A, const u16* __restrict__ Bb, u16* __restrict__ out,
    const int* __restrict__ perm, const int* __restrict__ off, int N, int bpt, int bcols)
{
    __shared__ u16 As[64][40];
    __shared__ u16 Bs[64][40];
    __shared__ int ridx[64];

    int t = blockIdx.y / bpt, bi = blockIdx.y % bpt;
    int i0 = off[t] + bi * 64, iend = off[t + 1];
    if (i0 >= iend) return;
    int tid = threadIdx.x;
    int col0 = blockIdx.x * 64;

    if (tid < 64) ridx[tid] = (i0 + tid < iend) ? perm[i0 + tid] : -1;
    __syncthreads();

    int sr = tid >> 2, sq = (tid & 3) * 8;
    int ar = ridx[sr];
    const float* asrc = A + (size_t)(ar < 0 ? 0 : ar) * CDIM + sq;
    const u16* bsrc = Bb + ((size_t)t * bcols + col0 + sr) * CDIM + sq;

    auto loadA = [&](int k0) -> uint4 {
        uint4 r = make_uint4(0, 0, 0, 0);
        if (ar >= 0) {
            float4 a0 = *(const float4*)(asrc + k0);
            float4 a1 = *(const float4*)(asrc + k0 + 4);
            r.x = (unsigned)f2b(a0.x) | ((unsigned)f2b(a0.y) << 16);
            r.y = (unsigned)f2b(a0.z) | ((unsigned)f2b(a0.w) << 16);
            r.z = (unsigned)f2b(a1.x) | ((unsigned)f2b(a1.y) << 16);
            r.w = (unsigned)f2b(a1.z) | ((unsigned)f2b(a1.w) << 16);
        }
        return r;
    };

    int lane = tid & 63, wid = tid >> 6;
    int wr = wid >> 1, wc = wid & 1;
    int l15 = lane & 15, lk = (lane >> 4) * 8;

    f32x4 acc00 = {0.f, 0.f, 0.f, 0.f}, acc01 = {0.f, 0.f, 0.f, 0.f};
    f32x4 acc10 = {0.f, 0.f, 0.f, 0.f}, acc11 = {0.f, 0.f, 0.f, 0.f};

    uint4 apre = loadA(0);
    uint4 bpre = *(const uint4*)(bsrc);

    for (int k0 = 0; k0 < CDIM; k0 += 32) {
        __syncthreads();
        *(uint4*)&As[sr][sq] = apre;
        *(uint4*)&Bs[sr][sq] = bpre;
        __syncthreads();

        if (k0 + 32 < CDIM) {
            apre = loadA(k0 + 32);
            bpre = *(const uint4*)(bsrc + k0 + 32);
        }

        s16x8 af0 = *(const s16x8*)&As[wr * 32 + l15][lk];
        s16x8 af1 = *(const s16x8*)&As[wr * 32 + 16 + l15][lk];
        s16x8 bf0 = *(const s16x8*)&Bs[wc * 32 + l15][lk];
        s16x8 bf1 = *(const s16x8*)&Bs[wc * 32 + 16 + l15][lk];

        acc00 = __builtin_amdgcn_mfma_f32_16x16x32_bf16(af0, bf0, acc00, 0, 0, 0);
        acc01 = __builtin_amdgcn_mfma_f32_16x16x32_bf16(af0, bf1, acc01, 0, 0, 0);
        acc10 = __builtin_amdgcn_mfma_f32_16x16x32_bf16(af1, bf0, acc10, 0, 0, 0);
        acc11 = __builtin_amdgcn_mfma_f32_16x16x32_bf16(af1, bf1, acc11, 0, 0, 0);
    }

    int rbase = wr * 32 + (lane >> 4) * 4;
#pragma unroll
    for (int mi = 0; mi < 2; ++mi) {
#pragma unroll
        for (int r = 0; r < 4; ++r) {
            int lrow = rbase + mi * 16 + r;
            int node = ridx[lrow];
            if (node < 0) continue;
            float v0 = (mi == 0) ? acc00[r] : acc10[r];
            float v1 = (mi == 0) ? acc01[r] : acc11[r];
            size_t b0 = (size_t)node * bcols + col0 + wc * 32 + l15;
            out[b0]      = f2b(v0);
            out[b0 + 16] = f2b(v1);
        }
    }
}

// ================= out GEMM: out = svn @ af_b (K=1280), 4 col-tiles in regs, A read once ======
__global__ __launch_bounds__(256) void outgemm_k(
    const u16* __restrict__ svn, const u16* __restrict__ af_b, float* __restrict__ out,
    const int* __restrict__ perm, const int* __restrict__ off, int N, int bpt,
    const float* __restrict__ x, const float* __restrict__ skip)
{
    __shared__ u16 As[64][36];
    __shared__ u16 Bs[4][64][36];
    __shared__ int ridx[64];

    int t = blockIdx.x / bpt, bi = blockIdx.x % bpt;
    int i0 = off[t] + bi * 64, iend = off[t + 1];
    if (i0 >= iend) return;
    int tid = threadIdx.x;
    if (tid < 64) ridx[tid] = (i0 + tid < iend) ? perm[i0 + tid] : -1;
    __syncthreads();

    int sr = tid >> 2, sq = (tid & 3) * 8;
    int ar = ridx[sr];
    const u16* asrc = svn + (size_t)(ar < 0 ? 0 : ar) * QWC + sq;
    const u16* bbase = af_b + (size_t)t * CDIM * QWC;

    int lane = tid & 63, wid = tid >> 6;
    int wr = wid >> 1, wc = wid & 1;
    int l15 = lane & 15, lk = (lane >> 4) * 8;

    f32x4 acc[4][2][2];
#pragma unroll
    for (int y = 0; y < 4; ++y)
#pragma unroll
        for (int mi = 0; mi < 2; ++mi)
#pragma unroll
            for (int ci = 0; ci < 2; ++ci)
                acc[y][mi][ci] = (f32x4){0.f, 0.f, 0.f, 0.f};

    uint4 apre = make_uint4(0, 0, 0, 0), bpre[4];
    if (ar >= 0) apre = *(const uint4*)(asrc);
#pragma unroll
    for (int y = 0; y < 4; ++y)
        bpre[y] = *(const uint4*)(bbase + (size_t)(y * 64 + sr) * QWC + sq);

    for (int kc = 0; kc < 40; ++kc) {
        __syncthreads();
        *(uint4*)&As[sr][sq] = apre;
#pragma unroll
        for (int y = 0; y < 4; ++y)
            *(uint4*)&Bs[y][sr][sq] = bpre[y];
        __syncthreads();

        if (kc + 1 < 40) {
            int ko = (kc + 1) * 32;
            if (ar >= 0) apre = *(const uint4*)(asrc + ko);
#pragma unroll
            for (int y = 0; y < 4; ++y)
                bpre[y] = *(const uint4*)(bbase + (size_t)(y * 64 + sr) * QWC + ko + sq);
        }

        s16x8 af0 = *(const s16x8*)&As[wr * 32 + l15][lk];
        s16x8 af1 = *(const s16x8*)&As[wr * 32 + 16 + l15][lk];
#pragma unroll
        for (int y = 0; y < 4; ++y) {
            s16x8 bf0 = *(const s16x8*)&Bs[y][wc * 32 + l15][lk];
            s16x8 bf1 = *(const s16x8*)&Bs[y][wc * 32 + 16 + l15][lk];
            acc[y][0][0] = __builtin_amdgcn_mfma_f32_16x16x32_bf16(af0, bf0, acc[y][0][0], 0, 0, 0);
            acc[y][0][1] = __builtin_amdgcn_mfma_f32_16x16x32_bf16(af0, bf1, acc[y][0][1], 0, 0, 0);
            acc[y][1][0] = __builtin_amdgcn_mfma_f32_16x16x32_bf16(af1, bf0, acc[y][1][0], 0, 0, 0);
            acc[y][1][1] = __builtin_amdgcn_mfma_f32_16x16x32_bf16(af1, bf1, acc[y][1][1], 0, 0, 0);
        }
    }

    float alpha = 1.f / (1.f + __expf(-skip[t]));
    float beta = 1.f - alpha;
    int rbase = wr * 32 + (lane >> 4) * 4;
#pragma unroll
    for (int y = 0; y < 4; ++y) {
        int c0i = y * 64 + wc * 32 + l15;
#pragma unroll
        for (int mi = 0; mi < 2; ++mi) {
#pragma unroll
            for (int r = 0; r < 4; ++r) {
                int node = ridx[rbase + mi * 16 + r];
                if (node < 0) continue;
                size_t b0 = (size_t)node * CDIM + c0i;
                out[b0]      = acc[y][mi][0][r] * alpha + x[b0] * beta;
                out[b0 + 16] = acc[y][mi][1][r] * alpha + x[b0 + 16] * beta;
            }
        }
    }
}

// ================= gather: one wave per dst; Sv in regs across ets; svn in-place =========
__global__ __launch_bounds__(256) void gather2_k(
    const u16* __restrict__ kb, const u16* __restrict__ vb, u16* __restrict__ qwsv,
    const float* __restrict__ pri, const int* __restrict__ rowptr, const int* __restrict__ epay,
    int N)
{
    int d = (blockIdx.x * 256 + threadIdx.x) >> 6;
    if (d >= N) return;
    int lane = threadIdx.x & 63, h = lane >> 3;
    const float rsD = 0.17677669529663687f;
    float dsum = 0.f;
    size_t rowb = (size_t)d * QWC + lane * 4;

    float Sv[ET][4];
#pragma unroll
    for (int et = 0; et < ET; ++et) { Sv[et][0] = Sv[et][1] = Sv[et][2] = Sv[et][3] = 0.f; }

#pragma unroll
    for (int et = 0; et < ET; ++et) {
        int key = d * ET + et;
        int p0 = rowptr[key], p1 = rowptr[key + 1];
        if (p0 >= p1) continue;
        float prif = pri[et * HD + h] * rsD;
        ushort4 qu = *(const ushort4*)(qwsv + rowb + et * 256);
        float q0 = b2f(qu.x), q1 = b2f(qu.y), q2 = b2f(qu.z), q3 = b2f(qu.w);
        for (int p = p0; p < p1; ++p) {
            int s = epay[p];
            ushort4 ku = *(const ushort4*)(kb + (size_t)s * CDIM + lane * 4);
            float tt = b2f(ku.x) * q0 + b2f(ku.y) * q1 + b2f(ku.z) * q2 + b2f(ku.w) * q3;
            tt += __shfl_xor(tt, 1, 8);
            tt += __shfl_xor(tt, 2, 8);
            tt += __shfl_xor(tt, 4, 8);
            float ex = __expf(tt * prif);
            ushort4 vu = *(const ushort4*)(vb + (size_t)s * CDIM + lane * 4);
            Sv[et][0] += ex * b2f(vu.x); Sv[et][1] += ex * b2f(vu.y);
            Sv[et][2] += ex * b2f(vu.z); Sv[et][3] += ex * b2f(vu.w);
            dsum += ex;
        }
    }

    float inv = dsum > 0.f ? 1.f / dsum : 0.f;
#pragma unroll
    for (int et = 0; et < ET; ++et) {
        ushort4 o;
        o.x = f2b(Sv[et][0] * inv); o.y = f2b(Sv[et][1] * inv);
        o.z = f2b(Sv[et][2] * inv); o.w = f2b(Sv[et][3] * inv);
        *(ushort4*)(qwsv + rowb + et * 256) = o;
    }
}

// ================= launch =================
extern "C" void kernel_launch(void* const* d_in, const int* in_sizes, int n_in,
                              void* d_out, int out_size, void* d_ws, size_t ws_size,
                              hipStream_t stream) {
    const float* x    = (const float*)d_in[0];
    const float* Wk   = (const float*)d_in[1];
    const float* Wq   = (const float*)d_in[2];
    const float* Wv   = (const float*)d_in[3];
    const float* Ratt = (const float*)d_in[4];
    const float* Rmsg = (const float*)d_in[5];
    const float* pri  = (const float*)d_in[6];
    const float* Wa   = (const float*)d_in[7];
    const float* skip = (const float*)d_in[8];
    const int* src   = (const int*)d_in[9];
    const int* dst   = (const int*)d_in[10];
    const int* etype = (const int*)d_in[11];
    const int* ntype = (const int*)d_in[12];

    int N = in_sizes[12];
    int E = in_sizes[9];
    const size_t NC = (size_t)N * CDIM;
    const int KEYS = N * ET;
    const int NB = (KEYS + 255) / 256;
    const int nblk = (N + 255) / 256;
    const size_t WTE = (size_t)NT * CDIM * CDIM;       // per weight tensor (u16 elems)
    const size_t QFE = (size_t)NT * QWC * CDIM;        // folded tensors (u16 elems)

    // ---- workspace (~190 MB) ----
    u16* kb   = (u16*)d_ws;                  // NC
    u16* vb   = kb + NC;                     // NC
    u16* qwsv = vb + NC;                     // 5*NC (qw then svn, in-place)
    u16* wtb  = qwsv + 5 * NC;               // 2*WTE (Wk, Wv transposed bf16)
    u16* qf_b = wtb + 2 * WTE;               // QFE
    u16* af_b = qf_b + QFE;                  // QFE
    int* rowptr = (int*)(af_b + QFE);        // KEYS+1  (persistent)
    int* perm   = rowptr + KEYS + 1;         // N       (persistent)
    int* epay   = perm + N;                  // E       (persistent)
    int* off    = epay + E;                  // NT+1    (persistent)
    // setup-only ints aliased into qwsv (dead before the qw GEMM writes it)
    int* khist = (int*)qwsv;                 // KEYS (zeroed)
    int* kscan = khist + KEYS;               // KEYS
    int* bsum  = kscan + KEYS;               // 1024
    int* bcnt  = bsum + 1024;                // NT*nblk
    int* base  = bcnt + NT * nblk;           // NT*nblk

    hipMemsetAsync(khist, 0, (size_t)KEYS * sizeof(int), stream);

    // node buckets (atomic-free, stable)
    bhist_k<<<nblk, 256, 0, stream>>>(ntype, N, nblk, bcnt);
    bscan_k<<<1, 1024, 0, stream>>>(bcnt, base, off, NT * nblk, nblk, N);
    bscatter_k<<<nblk, 256, 0, stream>>>(ntype, N, nblk, base, perm);

    // edge counting sort by (dst, etype) -> CSR
    ehist_k<<<(E + 255) / 256, 256, 0, stream>>>(dst, etype, E, khist);
    kscan1_k<<<NB, 256, 0, stream>>>(khist, kscan, bsum, KEYS);
    kscan2_k<<<1, 1024, 0, stream>>>(bsum, NB);
    kscan3_k<<<NB, 256, 0, stream>>>(kscan, bsum, KEYS);
    rowptr_k<<<(KEYS + 256) / 256, 256, 0, stream>>>(kscan, rowptr, KEYS, E);
    escatter_k<<<(E + 255) / 256, 256, 0, stream>>>(src, dst, etype, E, kscan, epay);

    // weight prep: Wk/Wv transpose->bf16; folded Wq*Ratt and Rmsg*Wa
    dim3 wg(4, 4, NT);
    wconv_k<<<wg, 256, 0, stream>>>(Wk, wtb + 0 * WTE);
    wconv_k<<<wg, 256, 0, stream>>>(Wv, wtb + 1 * WTE);
    qfold_k<<<NT * ET * HD, 256, 0, stream>>>(Wq, Ratt, qf_b);
    afold_k<<<NT * ET * HD, 256, 0, stream>>>(Wa, Rmsg, af_b);

    int bpt = (N + 63) / 64;

    // k, v projections (col-tiles on fast grid axis -> A stays L2-hot)
    gemm2_k<<<dim3(4, NT * bpt), 256, 0, stream>>>(x, wtb + 0 * WTE, kb, perm, off, N, bpt, CDIM);
    gemm2_k<<<dim3(4, NT * bpt), 256, 0, stream>>>(x, wtb + 1 * WTE, vb, perm, off, N, bpt, CDIM);

    // qw = x @ (Wq*Ratt) -> qwsv [N][1280]  (overwrites the aliased setup ints)
    gemm2_k<<<dim3(QWC / 64, NT * bpt), 256, 0, stream>>>(x, qf_b, qwsv, perm, off, N, bpt, QWC);

    // edge gather: svn (attn-weighted, den-normalized v-sums) in-place over qw
    gather2_k<<<(N * 64 + 255) / 256, 256, 0, stream>>>(kb, vb, qwsv, pri, rowptr, epay, N);

    // out = svn @ (Rmsg*Wa) with sigmoid-gated skip (K = 1280, A read once)
    outgemm_k<<<NT * bpt, 256, 0, stream>>>(qwsv, af_b, (float*)d_out, perm, off, N, bpt,
                                            x, skip);
}

// Round 12
// 486.209 us; speedup vs baseline: 1.5705x; 1.2558x over previous
//
#include <hip/hip_runtime.h>
#include <math.h>

#define CDIM 256
#define HD 8
#define DD 32
#define NT 3
#define ET 5
#define QWC (ET * CDIM)     // 1280

typedef unsigned short u16;
typedef __attribute__((ext_vector_type(8))) short s16x8;
typedef __attribute__((ext_vector_type(4))) float f32x4;

__device__ __forceinline__ float b2f(u16 u) { return __uint_as_float(((unsigned)u) << 16); }
__device__ __forceinline__ u16 f2b(float x) {
    unsigned u = __float_as_uint(x);
    return (u16)((u + 0x7FFF + ((u >> 16) & 1)) >> 16);
}

// ================= node-type buckets (atomic-free, stable) =================
__global__ void bhist_k(const int* __restrict__ ntype, int N, int nblk, int* __restrict__ bcnt) {
    __shared__ int wc[4][NT];
    int b = blockIdx.x, tid = threadIdx.x, lane = tid & 63, w = tid >> 6;
    int i = b * 256 + tid;
    int t = (i < N) ? ntype[i] : -1;
#pragma unroll
    for (int r = 0; r < NT; ++r) {
        unsigned long long m = __ballot(t == r);
        if (lane == 0) wc[w][r] = __popcll(m);
    }
    __syncthreads();
    if (tid < NT) bcnt[tid * nblk + b] = wc[0][tid] + wc[1][tid] + wc[2][tid] + wc[3][tid];
}

__global__ void bscan_k(const int* __restrict__ bcnt, int* __restrict__ base,
                        int* __restrict__ off, int total, int nblk, int N) {
    __shared__ int s[1024];
    int t = threadIdx.x;
    int v = (t < total) ? bcnt[t] : 0;
    s[t] = v; __syncthreads();
    for (int o = 1; o < 1024; o <<= 1) {
        int u = (t >= o) ? s[t - o] : 0; __syncthreads();
        s[t] += u; __syncthreads();
    }
    if (t < total) base[t] = s[t] - v;
    if (t < NT) off[t] = s[t * nblk] - bcnt[t * nblk];
    if (t == NT) off[NT] = N;
}

__global__ void bscatter_k(const int* __restrict__ ntype, int N, int nblk,
                           const int* __restrict__ base, int* __restrict__ perm) {
    __shared__ int wc[4][NT];
    __shared__ int woff[4][NT];
    int b = blockIdx.x, tid = threadIdx.x, lane = tid & 63, w = tid >> 6;
    int i = b * 256 + tid;
    int t = (i < N) ? ntype[i] : -1;
    unsigned long long mlt = (1ULL << lane) - 1;
    int rank = 0;
#pragma unroll
    for (int r = 0; r < NT; ++r) {
        unsigned long long m = __ballot(t == r);
        if (lane == 0) wc[w][r] = __popcll(m);
        if (t == r) rank = __popcll(m & mlt);
    }
    __syncthreads();
    if (tid == 0) {
#pragma unroll
        for (int r = 0; r < NT; ++r) {
            int a = 0;
#pragma unroll
            for (int w0 = 0; w0 < 4; ++w0) { woff[w0][r] = a; a += wc[w0][r]; }
        }
    }
    __syncthreads();
    if (t >= 0) perm[base[t * nblk + b] + woff[w][t] + rank] = i;
}

// ================= edge counting sort by key = dst*ET + etype =================
__global__ void ehist_k(const int* __restrict__ dst, const int* __restrict__ etype, int E,
                        int* __restrict__ khist) {
    int i = blockIdx.x * 256 + threadIdx.x;
    if (i < E) atomicAdd(&khist[dst[i] * ET + etype[i]], 1);
}

__global__ void kscan1_k(const int* __restrict__ khist, int* __restrict__ kscan,
                         int* __restrict__ bsum, int KEYS) {
    __shared__ int s[256];
    int b = blockIdx.x, t = threadIdx.x, i = b * 256 + t;
    int v = (i < KEYS) ? khist[i] : 0;
    s[t] = v; __syncthreads();
    for (int o = 1; o < 256; o <<= 1) {
        int u = (t >= o) ? s[t - o] : 0; __syncthreads();
        s[t] += u; __syncthreads();
    }
    if (i < KEYS) kscan[i] = s[t] - v;
    if (t == 255) bsum[b] = s[t];
}

__global__ void kscan2_k(int* __restrict__ bsum, int NB) {
    __shared__ int s[1024];
    int t = threadIdx.x;
    int v = (t < NB) ? bsum[t] : 0;
    s[t] = v; __syncthreads();
    for (int o = 1; o < 1024; o <<= 1) {
        int u = (t >= o) ? s[t - o] : 0; __syncthreads();
        s[t] += u; __syncthreads();
    }
    if (t < NB) bsum[t] = s[t] - v;
}

__global__ void kscan3_k(int* __restrict__ kscan, const int* __restrict__ bsum, int KEYS) {
    int i = blockIdx.x * 256 + threadIdx.x;
    if (i < KEYS) kscan[i] += bsum[blockIdx.x];
}

__global__ void rowptr_k(const int* __restrict__ kscan, int* __restrict__ rowptr, int KEYS, int E) {
    int i = blockIdx.x * 256 + threadIdx.x;
    if (i < KEYS) rowptr[i] = kscan[i];
    if (i == KEYS) rowptr[KEYS] = E;
}

__global__ void escatter_k(const int* __restrict__ src, const int* __restrict__ dst,
                           const int* __restrict__ etype, int E,
                           int* __restrict__ kscan, int* __restrict__ epay) {
    int e = blockIdx.x * 256 + threadIdx.x;
    if (e < E) {
        int pos = atomicAdd(&kscan[dst[e] * ET + etype[e]], 1);
        epay[pos] = src[e];
    }
}

// ================= W[t][k][c] f32 -> Wtb[t][c][k] bf16 =================
__global__ __launch_bounds__(256) void wconv_k(const float* __restrict__ W, u16* __restrict__ Wtb) {
    __shared__ u16 s[64][72];
    int k0 = blockIdx.x * 64, c0 = blockIdx.y * 64, t = blockIdx.z;
    const float* Wp = W + (size_t)t * CDIM * CDIM;
    int r = threadIdx.x >> 2, q = (threadIdx.x & 3) * 16;
#pragma unroll
    for (int m = 0; m < 16; m += 4) {
        float4 v = *(const float4*)(Wp + (size_t)(k0 + r) * CDIM + c0 + q + m);
        s[r][q + m + 0] = f2b(v.x); s[r][q + m + 1] = f2b(v.y);
        s[r][q + m + 2] = f2b(v.z); s[r][q + m + 3] = f2b(v.w);
    }
    __syncthreads();
    int c = threadIdx.x >> 2, kq = (threadIdx.x & 3) * 16;
    u16* op = Wtb + ((size_t)t * CDIM + c0 + c) * CDIM + k0 + kq;
#pragma unroll
    for (int m = 0; m < 16; m += 4) {
        ushort4 o;
        o.x = s[kq + m + 0][c]; o.y = s[kq + m + 1][c];
        o.z = s[kq + m + 2][c]; o.w = s[kq + m + 3][c];
        *(ushort4*)(op + m) = o;
    }
}

// ===== fold Ratt into Wq: qf_b[t][et*256+h*32+m][c] = sum_f Wq[t][c][h32+f]*Ratt[et,h,m,f]
__global__ __launch_bounds__(256) void qfold_k(const float* __restrict__ Wq,
                                               const float* __restrict__ Ratt,
                                               u16* __restrict__ qf_b) {
    __shared__ float Ra[DD][DD];   // [m][f]
    int b = blockIdx.x;            // t*(ET*HD) + et*HD + h
    int t = b / (ET * HD);
    int eh = b % (ET * HD);
    int et = eh >> 3, h = eh & 7;
    int tid = threadIdx.x;

    ((float4*)&Ra[0][0])[tid] = ((const float4*)(Ratt + (size_t)eh * (DD * DD)))[tid];
    __syncthreads();

    int c = tid;
    const float* wr = Wq + (size_t)t * (CDIM * CDIM) + (size_t)c * CDIM + h * DD;
    float wrow[DD];
#pragma unroll
    for (int f = 0; f < DD; f += 4) {
        float4 v = *(const float4*)(wr + f);
        wrow[f] = v.x; wrow[f + 1] = v.y; wrow[f + 2] = v.z; wrow[f + 3] = v.w;
    }
    for (int m = 0; m < DD; ++m) {
        float acc = 0.f;
#pragma unroll
        for (int f = 0; f < DD; ++f) acc += wrow[f] * Ra[m][f];
        qf_b[((size_t)t * QWC + et * 256 + h * 32 + m) * CDIM + c] = f2b(acc);
    }
}

// ===== fold Rmsg into Wa: af_b[t][col][et*256+h*32+f] = sum_m Rmsg[et,h,f,m]*Wa[t][h32+m][col]
__global__ __launch_bounds__(256) void afold_k(const float* __restrict__ Wa,
                                               const float* __restrict__ Rmsg,
                                               u16* __restrict__ af_b) {
    __shared__ float Rm[DD][DD];   // [f][m]
    int b = blockIdx.x;
    int t = b / (ET * HD);
    int eh = b % (ET * HD);
    int et = eh >> 3, h = eh & 7;
    int tid = threadIdx.x;

    ((float4*)&Rm[0][0])[tid] = ((const float4*)(Rmsg + (size_t)eh * (DD * DD)))[tid];
    __syncthreads();

    int col = tid;
    float wcol[DD];
#pragma unroll
    for (int m = 0; m < DD; ++m)
        wcol[m] = Wa[(size_t)t * (CDIM * CDIM) + (size_t)(h * 32 + m) * CDIM + col];

    u16* op = af_b + ((size_t)t * CDIM + col) * QWC + et * 256 + h * 32;
    for (int f = 0; f < DD; ++f) {
        float acc = 0.f;
#pragma unroll
        for (int m = 0; m < DD; ++m) acc += Rm[f][m] * wcol[m];
        op[f] = f2b(acc);
    }
}

// ================= MFMA typed GEMM: out[perm[r]] = bf16( A[perm[r]] @ B[t] ) =================
// Grid: (bcols/64, NT*bpt) — col-tiles fastest so A-tile stays L2-hot across them.
__global__ __launch_bounds__(256) void gemm2_k(
    const float* __restrict__ A, const u16* __restrict__ Bb, u16* __restrict__ out,
    const int* __restrict__ perm, const int* __restrict__ off, int N, int bpt, int bcols)
{
    __shared__ u16 As[64][40];
    __shared__ u16 Bs[64][40];
    __shared__ int ridx[64];

    int t = blockIdx.y / bpt, bi = blockIdx.y % bpt;
    int i0 = off[t] + bi * 64, iend = off[t + 1];
    if (i0 >= iend) return;
    int tid = threadIdx.x;
    int col0 = blockIdx.x * 64;

    if (tid < 64) ridx[tid] = (i0 + tid < iend) ? perm[i0 + tid] : -1;
    __syncthreads();

    int sr = tid >> 2, sq = (tid & 3) * 8;
    int ar = ridx[sr];
    const float* asrc = A + (size_t)(ar < 0 ? 0 : ar) * CDIM + sq;
    const u16* bsrc = Bb + ((size_t)t * bcols + col0 + sr) * CDIM + sq;

    auto loadA = [&](int k0) -> uint4 {
        uint4 r = make_uint4(0, 0, 0, 0);
        if (ar >= 0) {
            float4 a0 = *(const float4*)(asrc + k0);
            float4 a1 = *(const float4*)(asrc + k0 + 4);
            r.x = (unsigned)f2b(a0.x) | ((unsigned)f2b(a0.y) << 16);
            r.y = (unsigned)f2b(a0.z) | ((unsigned)f2b(a0.w) << 16);
            r.z = (unsigned)f2b(a1.x) | ((unsigned)f2b(a1.y) << 16);
            r.w = (unsigned)f2b(a1.z) | ((unsigned)f2b(a1.w) << 16);
        }
        return r;
    };

    int lane = tid & 63, wid = tid >> 6;
    int wr = wid >> 1, wc = wid & 1;
    int l15 = lane & 15, lk = (lane >> 4) * 8;

    f32x4 acc00 = {0.f, 0.f, 0.f, 0.f}, acc01 = {0.f, 0.f, 0.f, 0.f};
    f32x4 acc10 = {0.f, 0.f, 0.f, 0.f}, acc11 = {0.f, 0.f, 0.f, 0.f};

    uint4 apre = loadA(0);
    uint4 bpre = *(const uint4*)(bsrc);

    for (int k0 = 0; k0 < CDIM; k0 += 32) {
        __syncthreads();
        *(uint4*)&As[sr][sq] = apre;
        *(uint4*)&Bs[sr][sq] = bpre;
        __syncthreads();

        if (k0 + 32 < CDIM) {
            apre = loadA(k0 + 32);
            bpre = *(const uint4*)(bsrc + k0 + 32);
        }

        s16x8 af0 = *(const s16x8*)&As[wr * 32 + l15][lk];
        s16x8 af1 = *(const s16x8*)&As[wr * 32 + 16 + l15][lk];
        s16x8 bf0 = *(const s16x8*)&Bs[wc * 32 + l15][lk];
        s16x8 bf1 = *(const s16x8*)&Bs[wc * 32 + 16 + l15][lk];

        acc00 = __builtin_amdgcn_mfma_f32_16x16x32_bf16(af0, bf0, acc00, 0, 0, 0);
        acc01 = __builtin_amdgcn_mfma_f32_16x16x32_bf16(af0, bf1, acc01, 0, 0, 0);
        acc10 = __builtin_amdgcn_mfma_f32_16x16x32_bf16(af1, bf0, acc10, 0, 0, 0);
        acc11 = __builtin_amdgcn_mfma_f32_16x16x32_bf16(af1, bf1, acc11, 0, 0, 0);
    }

    int rbase = wr * 32 + (lane >> 4) * 4;
#pragma unroll
    for (int mi = 0; mi < 2; ++mi) {
#pragma unroll
        for (int r = 0; r < 4; ++r) {
            int lrow = rbase + mi * 16 + r;
            int node = ridx[lrow];
            if (node < 0) continue;
            float v0 = (mi == 0) ? acc00[r] : acc10[r];
            float v1 = (mi == 0) ? acc01[r] : acc11[r];
            size_t b0 = (size_t)node * bcols + col0 + wc * 32 + l15;
            out[b0]      = f2b(v0);
            out[b0 + 16] = f2b(v1);
        }
    }
}

// ================= out GEMM v3: out = svn @ af_b (K=1280) =================
// BK=64 (full-line A staging); A-only LDS (9 KB); each wave owns a 64-col output
// stripe and reads its B fragments directly from L2-resident af_b. 32 MFMA/wave/chunk.
__global__ __launch_bounds__(256) void outgemm_k(
    const u16* __restrict__ svn, const u16* __restrict__ af_b, float* __restrict__ out,
    const int* __restrict__ perm, const int* __restrict__ off, int N, int bpt,
    const float* __restrict__ x, const float* __restrict__ skip)
{
    __shared__ u16 As[64][68];
    __shared__ int ridx[64];

    int t = blockIdx.x / bpt, bi = blockIdx.x % bpt;
    int i0 = off[t] + bi * 64, iend = off[t + 1];
    if (i0 >= iend) return;
    int tid = threadIdx.x;
    if (tid < 64) ridx[tid] = (i0 + tid < iend) ? perm[i0 + tid] : -1;
    __syncthreads();

    int lane = tid & 63, y = tid >> 6;       // wave y owns out cols [y*64, y*64+64)
    int l15 = lane & 15, lq = lane >> 4;
    int lk = lq * 8;

    int sr = tid >> 2, sc = (tid & 3) * 16;  // staging: 4 threads/row, 32 B each (128 B/row)
    int ar = ridx[sr];
    const u16* asrc = svn + (size_t)(ar < 0 ? 0 : ar) * QWC + sc;
    const u16* bbase = af_b + ((size_t)t * CDIM + y * 64) * QWC;

    f32x4 acc[4][4];   // [mi][ci]
#pragma unroll
    for (int mi = 0; mi < 4; ++mi)
#pragma unroll
        for (int ci = 0; ci < 4; ++ci)
            acc[mi][ci] = (f32x4){0.f, 0.f, 0.f, 0.f};

    uint4 apre0 = make_uint4(0, 0, 0, 0), apre1 = make_uint4(0, 0, 0, 0);
    if (ar >= 0) {
        apre0 = *(const uint4*)(asrc);
        apre1 = *(const uint4*)(asrc + 8);
    }

    for (int kc = 0; kc < 20; ++kc) {
        __syncthreads();
        *(uint4*)&As[sr][sc] = apre0;
        *(uint4*)&As[sr][sc + 8] = apre1;
        __syncthreads();
        if (kc + 1 < 20) {
            int ko = (kc + 1) * 64;
            if (ar >= 0) {
                apre0 = *(const uint4*)(asrc + ko);
                apre1 = *(const uint4*)(asrc + ko + 8);
            }
        }

        // B fragments direct from global (af_b ~640 KB/type, L2-resident)
        int kbase = kc * 64;
        s16x8 bf0[4], bf1[4];
#pragma unroll
        for (int ci = 0; ci < 4; ++ci) {
            const u16* bp = bbase + (size_t)(ci * 16 + l15) * QWC + kbase;
            bf0[ci] = *(const s16x8*)(bp + lk);
            bf1[ci] = *(const s16x8*)(bp + 32 + lk);
        }

#pragma unroll
        for (int mi = 0; mi < 4; ++mi) {
            s16x8 af0 = *(const s16x8*)&As[mi * 16 + l15][lk];
            s16x8 af1 = *(const s16x8*)&As[mi * 16 + l15][32 + lk];
#pragma unroll
            for (int ci = 0; ci < 4; ++ci) {
                acc[mi][ci] = __builtin_amdgcn_mfma_f32_16x16x32_bf16(af0, bf0[ci], acc[mi][ci], 0, 0, 0);
                acc[mi][ci] = __builtin_amdgcn_mfma_f32_16x16x32_bf16(af1, bf1[ci], acc[mi][ci], 0, 0, 0);
            }
        }
    }

    float alpha = 1.f / (1.f + __expf(-skip[t]));
    float beta = 1.f - alpha;
#pragma unroll
    for (int mi = 0; mi < 4; ++mi) {
#pragma unroll
        for (int r = 0; r < 4; ++r) {
            int node = ridx[mi * 16 + lq * 4 + r];
            if (node < 0) continue;
#pragma unroll
            for (int ci = 0; ci < 4; ++ci) {
                size_t b0 = (size_t)node * CDIM + y * 64 + ci * 16 + l15;
                out[b0] = acc[mi][ci][r] * alpha + x[b0] * beta;
            }
        }
    }
}

// ================= gather: one wave per dst; Sv in regs across ets; svn in-place =========
__global__ __launch_bounds__(256) void gather2_k(
    const u16* __restrict__ kb, const u16* __restrict__ vb, u16* __restrict__ qwsv,
    const float* __restrict__ pri, const int* __restrict__ rowptr, const int* __restrict__ epay,
    int N)
{
    int d = (blockIdx.x * 256 + threadIdx.x) >> 6;
    if (d >= N) return;
    int lane = threadIdx.x & 63, h = lane >> 3;
    const float rsD = 0.17677669529663687f;
    float dsum = 0.f;
    size_t rowb = (size_t)d * QWC + lane * 4;

    float Sv[ET][4];
#pragma unroll
    for (int et = 0; et < ET; ++et) { Sv[et][0] = Sv[et][1] = Sv[et][2] = Sv[et][3] = 0.f; }

#pragma unroll
    for (int et = 0; et < ET; ++et) {
        int key = d * ET + et;
        int p0 = rowptr[key], p1 = rowptr[key + 1];
        if (p0 >= p1) continue;
        float prif = pri[et * HD + h] * rsD;
        ushort4 qu = *(const ushort4*)(qwsv + rowb + et * 256);
        float q0 = b2f(qu.x), q1 = b2f(qu.y), q2 = b2f(qu.z), q3 = b2f(qu.w);
        for (int p = p0; p < p1; ++p) {
            int s = epay[p];
            ushort4 ku = *(const ushort4*)(kb + (size_t)s * CDIM + lane * 4);
            float tt = b2f(ku.x) * q0 + b2f(ku.y) * q1 + b2f(ku.z) * q2 + b2f(ku.w) * q3;
            tt += __shfl_xor(tt, 1, 8);
            tt += __shfl_xor(tt, 2, 8);
            tt += __shfl_xor(tt, 4, 8);
            float ex = __expf(tt * prif);
            ushort4 vu = *(const ushort4*)(vb + (size_t)s * CDIM + lane * 4);
            Sv[et][0] += ex * b2f(vu.x); Sv[et][1] += ex * b2f(vu.y);
            Sv[et][2] += ex * b2f(vu.z); Sv[et][3] += ex * b2f(vu.w);
            dsum += ex;
        }
    }

    float inv = dsum > 0.f ? 1.f / dsum : 0.f;
#pragma unroll
    for (int et = 0; et < ET; ++et) {
        ushort4 o;
        o.x = f2b(Sv[et][0] * inv); o.y = f2b(Sv[et][1] * inv);
        o.z = f2b(Sv[et][2] * inv); o.w = f2b(Sv[et][3] * inv);
        *(ushort4*)(qwsv + rowb + et * 256) = o;
    }
}

// ================= launch =================
extern "C" void kernel_launch(void* const* d_in, const int* in_sizes, int n_in,
                              void* d_out, int out_size, void* d_ws, size_t ws_size,
                              hipStream_t stream) {
    const float* x    = (const float*)d_in[0];
    const float* Wk   = (const float*)d_in[1];
    const float* Wq   = (const float*)d_in[2];
    const float* Wv   = (const float*)d_in[3];
    const float* Ratt = (const float*)d_in[4];
    const float* Rmsg = (const float*)d_in[5];
    const float* pri  = (const float*)d_in[6];
    const float* Wa   = (const float*)d_in[7];
    const float* skip = (const float*)d_in[8];
    const int* src   = (const int*)d_in[9];
    const int* dst   = (const int*)d_in[10];
    const int* etype = (const int*)d_in[11];
    const int* ntype = (const int*)d_in[12];

    int N = in_sizes[12];
    int E = in_sizes[9];
    const size_t NC = (size_t)N * CDIM;
    const int KEYS = N * ET;
    const int NB = (KEYS + 255) / 256;
    const int nblk = (N + 255) / 256;
    const size_t WTE = (size_t)NT * CDIM * CDIM;       // per weight tensor (u16 elems)
    const size_t QFE = (size_t)NT * QWC * CDIM;        // folded tensors (u16 elems)

    // ---- workspace (~190 MB) ----
    u16* kb   = (u16*)d_ws;                  // NC
    u16* vb   = kb + NC;                     // NC
    u16* qwsv = vb + NC;                     // 5*NC (qw then svn, in-place)
    u16* wtb  = qwsv + 5 * NC;               // 2*WTE (Wk, Wv transposed bf16)
    u16* qf_b = wtb + 2 * WTE;               // QFE
    u16* af_b = qf_b + QFE;                  // QFE
    int* rowptr = (int*)(af_b + QFE);        // KEYS+1  (persistent)
    int* perm   = rowptr + KEYS + 1;         // N       (persistent)
    int* epay   = perm + N;                  // E       (persistent)
    int* off    = epay + E;                  // NT+1    (persistent)
    // setup-only ints aliased into qwsv (dead before the qw GEMM writes it)
    int* khist = (int*)qwsv;                 // KEYS (zeroed)
    int* kscan = khist + KEYS;               // KEYS
    int* bsum  = kscan + KEYS;               // 1024
    int* bcnt  = bsum + 1024;                // NT*nblk
    int* base  = bcnt + NT * nblk;           // NT*nblk

    hipMemsetAsync(khist, 0, (size_t)KEYS * sizeof(int), stream);

    // node buckets (atomic-free, stable)
    bhist_k<<<nblk, 256, 0, stream>>>(ntype, N, nblk, bcnt);
    bscan_k<<<1, 1024, 0, stream>>>(bcnt, base, off, NT * nblk, nblk, N);
    bscatter_k<<<nblk, 256, 0, stream>>>(ntype, N, nblk, base, perm);

    // edge counting sort by (dst, etype) -> CSR
    ehist_k<<<(E + 255) / 256, 256, 0, stream>>>(dst, etype, E, khist);
    kscan1_k<<<NB, 256, 0, stream>>>(khist, kscan, bsum, KEYS);
    kscan2_k<<<1, 1024, 0, stream>>>(bsum, NB);
    kscan3_k<<<NB, 256, 0, stream>>>(kscan, bsum, KEYS);
    rowptr_k<<<(KEYS + 256) / 256, 256, 0, stream>>>(kscan, rowptr, KEYS, E);
    escatter_k<<<(E + 255) / 256, 256, 0, stream>>>(src, dst, etype, E, kscan, epay);

    // weight prep: Wk/Wv transpose->bf16; folded Wq*Ratt and Rmsg*Wa
    dim3 wg(4, 4, NT);
    wconv_k<<<wg, 256, 0, stream>>>(Wk, wtb + 0 * WTE);
    wconv_k<<<wg, 256, 0, stream>>>(Wv, wtb + 1 * WTE);
    qfold_k<<<NT * ET * HD, 256, 0, stream>>>(Wq, Ratt, qf_b);
    afold_k<<<NT * ET * HD, 256, 0, stream>>>(Wa, Rmsg, af_b);

    int bpt = (N + 63) / 64;

    // k, v projections (col-tiles on fast grid axis -> A stays L2-hot)
    gemm2_k<<<dim3(4, NT * bpt), 256, 0, stream>>>(x, wtb + 0 * WTE, kb, perm, off, N, bpt, CDIM);
    gemm2_k<<<dim3(4, NT * bpt), 256, 0, stream>>>(x, wtb + 1 * WTE, vb, perm, off, N, bpt, CDIM);

    // qw = x @ (Wq*Ratt) -> qwsv [N][1280]  (overwrites the aliased setup ints)
    gemm2_k<<<dim3(QWC / 64, NT * bpt), 256, 0, stream>>>(x, qf_b, qwsv, perm, off, N, bpt, QWC);

    // edge gather: svn (attn-weighted, den-normalized v-sums) in-place over qw
    gather2_k<<<(N * 64 + 255) / 256, 256, 0, stream>>>(kb, vb, qwsv, pri, rowptr, epay, N);

    // out = svn @ (Rmsg*Wa) with sigmoid-gated skip (K=1280, BK=64, direct-B)
    outgemm_k<<<NT * bpt, 256, 0, stream>>>(qwsv, af_b, (float*)d_out, perm, off, N, bpt,
                                            x, skip);
}

// Round 13
// 428.760 us; speedup vs baseline: 1.7809x; 1.1340x over previous
//
#include <hip/hip_runtime.h>
#include <math.h>

#define CDIM 256
#define HD 8
#define DD 32
#define NT 3
#define ET 5
#define QWC (ET * CDIM)     // 1280

typedef unsigned short u16;
typedef __attribute__((ext_vector_type(8))) short s16x8;
typedef __attribute__((ext_vector_type(4))) float f32x4;

__device__ __forceinline__ float b2f(u16 u) { return __uint_as_float(((unsigned)u) << 16); }
__device__ __forceinline__ u16 f2b(float x) {
    unsigned u = __float_as_uint(x);
    return (u16)((u + 0x7FFF + ((u >> 16) & 1)) >> 16);
}

// ================= node-type buckets (atomic-free, stable) =================
__global__ void bhist_k(const int* __restrict__ ntype, int N, int nblk, int* __restrict__ bcnt) {
    __shared__ int wc[4][NT];
    int b = blockIdx.x, tid = threadIdx.x, lane = tid & 63, w = tid >> 6;
    int i = b * 256 + tid;
    int t = (i < N) ? ntype[i] : -1;
#pragma unroll
    for (int r = 0; r < NT; ++r) {
        unsigned long long m = __ballot(t == r);
        if (lane == 0) wc[w][r] = __popcll(m);
    }
    __syncthreads();
    if (tid < NT) bcnt[tid * nblk + b] = wc[0][tid] + wc[1][tid] + wc[2][tid] + wc[3][tid];
}

__global__ void bscan_k(const int* __restrict__ bcnt, int* __restrict__ base,
                        int* __restrict__ off, int total, int nblk, int N) {
    __shared__ int s[1024];
    int t = threadIdx.x;
    int v = (t < total) ? bcnt[t] : 0;
    s[t] = v; __syncthreads();
    for (int o = 1; o < 1024; o <<= 1) {
        int u = (t >= o) ? s[t - o] : 0; __syncthreads();
        s[t] += u; __syncthreads();
    }
    if (t < total) base[t] = s[t] - v;
    if (t < NT) off[t] = s[t * nblk] - bcnt[t * nblk];
    if (t == NT) off[NT] = N;
}

__global__ void bscatter_k(const int* __restrict__ ntype, int N, int nblk,
                           const int* __restrict__ base, int* __restrict__ perm) {
    __shared__ int wc[4][NT];
    __shared__ int woff[4][NT];
    int b = blockIdx.x, tid = threadIdx.x, lane = tid & 63, w = tid >> 6;
    int i = b * 256 + tid;
    int t = (i < N) ? ntype[i] : -1;
    unsigned long long mlt = (1ULL << lane) - 1;
    int rank = 0;
#pragma unroll
    for (int r = 0; r < NT; ++r) {
        unsigned long long m = __ballot(t == r);
        if (lane == 0) wc[w][r] = __popcll(m);
        if (t == r) rank = __popcll(m & mlt);
    }
    __syncthreads();
    if (tid == 0) {
#pragma unroll
        for (int r = 0; r < NT; ++r) {
            int a = 0;
#pragma unroll
            for (int w0 = 0; w0 < 4; ++w0) { woff[w0][r] = a; a += wc[w0][r]; }
        }
    }
    __syncthreads();
    if (t >= 0) perm[base[t * nblk + b] + woff[w][t] + rank] = i;
}

// ================= edge counting sort by key = dst*ET + etype =================
__global__ void ehist_k(const int* __restrict__ dst, const int* __restrict__ etype, int E,
                        int* __restrict__ khist) {
    int i = blockIdx.x * 256 + threadIdx.x;
    if (i < E) atomicAdd(&khist[dst[i] * ET + etype[i]], 1);
}

__global__ void kscan1_k(const int* __restrict__ khist, int* __restrict__ kscan,
                         int* __restrict__ bsum, int KEYS) {
    __shared__ int s[256];
    int b = blockIdx.x, t = threadIdx.x, i = b * 256 + t;
    int v = (i < KEYS) ? khist[i] : 0;
    s[t] = v; __syncthreads();
    for (int o = 1; o < 256; o <<= 1) {
        int u = (t >= o) ? s[t - o] : 0; __syncthreads();
        s[t] += u; __syncthreads();
    }
    if (i < KEYS) kscan[i] = s[t] - v;
    if (t == 255) bsum[b] = s[t];
}

__global__ void kscan2_k(int* __restrict__ bsum, int NB) {
    __shared__ int s[1024];
    int t = threadIdx.x;
    int v = (t < NB) ? bsum[t] : 0;
    s[t] = v; __syncthreads();
    for (int o = 1; o < 1024; o <<= 1) {
        int u = (t >= o) ? s[t - o] : 0; __syncthreads();
        s[t] += u; __syncthreads();
    }
    if (t < NB) bsum[t] = s[t] - v;
}

// merged: kscan += bsum, and rowptr = result (+ rowptr[KEYS] = E)
__global__ void kscan3r_k(int* __restrict__ kscan, const int* __restrict__ bsum,
                          int* __restrict__ rowptr, int KEYS, int E) {
    int i = blockIdx.x * 256 + threadIdx.x;
    if (i < KEYS) {
        int v = kscan[i] + bsum[blockIdx.x];
        kscan[i] = v;
        rowptr[i] = v;
    }
    if (i == 0) rowptr[KEYS] = E;
}

// epay packs (etype << 24) | src
__global__ void escatter_k(const int* __restrict__ src, const int* __restrict__ dst,
                           const int* __restrict__ etype, int E,
                           int* __restrict__ kscan, int* __restrict__ epay) {
    int e = blockIdx.x * 256 + threadIdx.x;
    if (e < E) {
        int et = etype[e];
        int pos = atomicAdd(&kscan[dst[e] * ET + et], 1);
        epay[pos] = (et << 24) | src[e];
    }
}

// ================= Wk|Wv [t][k][c] f32 -> Wtb[z][c][k] bf16 (z: 0..NT-1 = Wk, NT..2NT-1 = Wv)
__global__ __launch_bounds__(256) void wconv2_k(const float* __restrict__ Wk,
                                                const float* __restrict__ Wv,
                                                u16* __restrict__ Wtb) {
    __shared__ u16 s[64][72];
    int k0 = blockIdx.x * 64, c0 = blockIdx.y * 64, z = blockIdx.z;
    const float* Wp = (z < NT) ? (Wk + (size_t)z * CDIM * CDIM)
                               : (Wv + (size_t)(z - NT) * CDIM * CDIM);
    int r = threadIdx.x >> 2, q = (threadIdx.x & 3) * 16;
#pragma unroll
    for (int m = 0; m < 16; m += 4) {
        float4 v = *(const float4*)(Wp + (size_t)(k0 + r) * CDIM + c0 + q + m);
        s[r][q + m + 0] = f2b(v.x); s[r][q + m + 1] = f2b(v.y);
        s[r][q + m + 2] = f2b(v.z); s[r][q + m + 3] = f2b(v.w);
    }
    __syncthreads();
    int c = threadIdx.x >> 2, kq = (threadIdx.x & 3) * 16;
    u16* op = Wtb + ((size_t)z * CDIM + c0 + c) * CDIM + k0 + kq;
#pragma unroll
    for (int m = 0; m < 16; m += 4) {
        ushort4 o;
        o.x = s[kq + m + 0][c]; o.y = s[kq + m + 1][c];
        o.z = s[kq + m + 2][c]; o.w = s[kq + m + 3][c];
        *(ushort4*)(op + m) = o;
    }
}

// ===== merged folds. y=0: qf_b[t][et*256+h*32+m][c] = sum_f Wq[t][c][h32+f]*Ratt[et,h,m,f]
//                    y=1: af_b[t][col][et*256+h*32+f] = sum_m Rmsg[et,h,f,m]*Wa[t][h32+m][col]
__global__ __launch_bounds__(256) void rfold_k(const float* __restrict__ Wq,
                                               const float* __restrict__ Ratt,
                                               u16* __restrict__ qf_b,
                                               const float* __restrict__ Wa,
                                               const float* __restrict__ Rmsg,
                                               u16* __restrict__ af_b) {
    __shared__ float Rs[DD][DD];
    int b = blockIdx.x;
    int t = b / (ET * HD);
    int eh = b % (ET * HD);
    int et = eh >> 3, h = eh & 7;
    int tid = threadIdx.x;

    if (blockIdx.y == 0) {
        // Rs[m][f] = Ratt[et][h][m][f]  (transposed load below gives Rs[c4][r] pattern)
        float4 rv = ((const float4*)(Ratt + (size_t)eh * (DD * DD)))[tid];
        int r = tid >> 3, c4 = (tid & 7) * 4;
        Rs[r][c4 + 0] = rv.x; Rs[r][c4 + 1] = rv.y;
        Rs[r][c4 + 2] = rv.z; Rs[r][c4 + 3] = rv.w;   // Rs[m][f]
        __syncthreads();

        int c = tid;
        const float* wr = Wq + (size_t)t * (CDIM * CDIM) + (size_t)c * CDIM + h * DD;
        float wrow[DD];
#pragma unroll
        for (int f = 0; f < DD; f += 4) {
            float4 v = *(const float4*)(wr + f);
            wrow[f] = v.x; wrow[f + 1] = v.y; wrow[f + 2] = v.z; wrow[f + 3] = v.w;
        }
        for (int m = 0; m < DD; ++m) {
            float acc = 0.f;
#pragma unroll
            for (int f = 0; f < DD; ++f) acc += wrow[f] * Rs[m][f];
            qf_b[((size_t)t * QWC + et * 256 + h * 32 + m) * CDIM + c] = f2b(acc);
        }
    } else {
        // Rs[f][m] = Rmsg[et][h][f][m]
        float4 rv = ((const float4*)(Rmsg + (size_t)eh * (DD * DD)))[tid];
        int r = tid >> 3, c4 = (tid & 7) * 4;
        Rs[r][c4 + 0] = rv.x; Rs[r][c4 + 1] = rv.y;
        Rs[r][c4 + 2] = rv.z; Rs[r][c4 + 3] = rv.w;   // Rs[f][m]
        __syncthreads();

        int col = tid;
        float wcol[DD];
#pragma unroll
        for (int m = 0; m < DD; ++m)
            wcol[m] = Wa[(size_t)t * (CDIM * CDIM) + (size_t)(h * 32 + m) * CDIM + col];

        u16* op = af_b + ((size_t)t * CDIM + col) * QWC + et * 256 + h * 32;
        for (int f = 0; f < DD; ++f) {
            float acc = 0.f;
#pragma unroll
            for (int m = 0; m < DD; ++m) acc += Rs[f][m] * wcol[m];
            op[f] = f2b(acc);
        }
    }
}

// ================= fused projection GEMM: [k|v|qw] = x @ {Wk,Wv,Wq*Ratt} =================
// Grid (28, NT*bpt): col-tiles on fast axis -> 64-row A panel L2-hot across all 28 tiles.
__global__ __launch_bounds__(256) void gemmall_k(
    const float* __restrict__ A, const u16* __restrict__ wtb, const u16* __restrict__ qf_b,
    u16* __restrict__ kb, u16* __restrict__ vb, u16* __restrict__ qwsv,
    const int* __restrict__ perm, const int* __restrict__ off, int N, int bpt)
{
    __shared__ u16 As[64][40];
    __shared__ u16 Bs[64][40];
    __shared__ int ridx[64];

    int t = blockIdx.y / bpt, bi = blockIdx.y % bpt;
    int i0 = off[t] + bi * 64, iend = off[t + 1];
    if (i0 >= iend) return;
    int tid = threadIdx.x;

    int bx = blockIdx.x;
    u16* out; int ostr, oc0; const u16* bslab;
    const size_t CC = (size_t)CDIM * CDIM;
    if (bx < 4)      { out = kb;   ostr = CDIM; oc0 = bx * 64;       bslab = wtb + (size_t)t * CC; }
    else if (bx < 8) { out = vb;   ostr = CDIM; oc0 = (bx - 4) * 64; bslab = wtb + (size_t)(NT + t) * CC; }
    else             { out = qwsv; ostr = QWC;  oc0 = (bx - 8) * 64; bslab = qf_b + (size_t)t * QWC * CDIM; }

    if (tid < 64) ridx[tid] = (i0 + tid < iend) ? perm[i0 + tid] : -1;
    __syncthreads();

    int sr = tid >> 2, sq = (tid & 3) * 8;
    int ar = ridx[sr];
    const float* asrc = A + (size_t)(ar < 0 ? 0 : ar) * CDIM + sq;
    const u16* bsrc = bslab + (size_t)(oc0 + sr) * CDIM + sq;

    auto loadA = [&](int k0) -> uint4 {
        uint4 r = make_uint4(0, 0, 0, 0);
        if (ar >= 0) {
            float4 a0 = *(const float4*)(asrc + k0);
            float4 a1 = *(const float4*)(asrc + k0 + 4);
            r.x = (unsigned)f2b(a0.x) | ((unsigned)f2b(a0.y) << 16);
            r.y = (unsigned)f2b(a0.z) | ((unsigned)f2b(a0.w) << 16);
            r.z = (unsigned)f2b(a1.x) | ((unsigned)f2b(a1.y) << 16);
            r.w = (unsigned)f2b(a1.z) | ((unsigned)f2b(a1.w) << 16);
        }
        return r;
    };

    int lane = tid & 63, wid = tid >> 6;
    int wr = wid >> 1, wc = wid & 1;
    int l15 = lane & 15, lk = (lane >> 4) * 8;

    f32x4 acc00 = {0.f, 0.f, 0.f, 0.f}, acc01 = {0.f, 0.f, 0.f, 0.f};
    f32x4 acc10 = {0.f, 0.f, 0.f, 0.f}, acc11 = {0.f, 0.f, 0.f, 0.f};

    uint4 apre = loadA(0);
    uint4 bpre = *(const uint4*)(bsrc);

    for (int k0 = 0; k0 < CDIM; k0 += 32) {
        __syncthreads();
        *(uint4*)&As[sr][sq] = apre;
        *(uint4*)&Bs[sr][sq] = bpre;
        __syncthreads();

        if (k0 + 32 < CDIM) {
            apre = loadA(k0 + 32);
            bpre = *(const uint4*)(bsrc + k0 + 32);
        }

        s16x8 af0 = *(const s16x8*)&As[wr * 32 + l15][lk];
        s16x8 af1 = *(const s16x8*)&As[wr * 32 + 16 + l15][lk];
        s16x8 bf0 = *(const s16x8*)&Bs[wc * 32 + l15][lk];
        s16x8 bf1 = *(const s16x8*)&Bs[wc * 32 + 16 + l15][lk];

        acc00 = __builtin_amdgcn_mfma_f32_16x16x32_bf16(af0, bf0, acc00, 0, 0, 0);
        acc01 = __builtin_amdgcn_mfma_f32_16x16x32_bf16(af0, bf1, acc01, 0, 0, 0);
        acc10 = __builtin_amdgcn_mfma_f32_16x16x32_bf16(af1, bf0, acc10, 0, 0, 0);
        acc11 = __builtin_amdgcn_mfma_f32_16x16x32_bf16(af1, bf1, acc11, 0, 0, 0);
    }

    int rbase = wr * 32 + (lane >> 4) * 4;
#pragma unroll
    for (int mi = 0; mi < 2; ++mi) {
#pragma unroll
        for (int r = 0; r < 4; ++r) {
            int lrow = rbase + mi * 16 + r;
            int node = ridx[lrow];
            if (node < 0) continue;
            float v0 = (mi == 0) ? acc00[r] : acc10[r];
            float v1 = (mi == 0) ? acc01[r] : acc11[r];
            size_t b0 = (size_t)node * ostr + oc0 + wc * 32 + l15;
            out[b0]      = f2b(v0);
            out[b0 + 16] = f2b(v1);
        }
    }
}

// ================= out GEMM v3: out = svn @ af_b (K=1280) =================
__global__ __launch_bounds__(256) void outgemm_k(
    const u16* __restrict__ svn, const u16* __restrict__ af_b, float* __restrict__ out,
    const int* __restrict__ perm, const int* __restrict__ off, int N, int bpt,
    const float* __restrict__ x, const float* __restrict__ skip)
{
    __shared__ u16 As[64][68];
    __shared__ int ridx[64];

    int t = blockIdx.x / bpt, bi = blockIdx.x % bpt;
    int i0 = off[t] + bi * 64, iend = off[t + 1];
    if (i0 >= iend) return;
    int tid = threadIdx.x;
    if (tid < 64) ridx[tid] = (i0 + tid < iend) ? perm[i0 + tid] : -1;
    __syncthreads();

    int lane = tid & 63, y = tid >> 6;
    int l15 = lane & 15, lq = lane >> 4;
    int lk = lq * 8;

    int sr = tid >> 2, sc = (tid & 3) * 16;
    int ar = ridx[sr];
    const u16* asrc = svn + (size_t)(ar < 0 ? 0 : ar) * QWC + sc;
    const u16* bbase = af_b + ((size_t)t * CDIM + y * 64) * QWC;

    f32x4 acc[4][4];
#pragma unroll
    for (int mi = 0; mi < 4; ++mi)
#pragma unroll
        for (int ci = 0; ci < 4; ++ci)
            acc[mi][ci] = (f32x4){0.f, 0.f, 0.f, 0.f};

    uint4 apre0 = make_uint4(0, 0, 0, 0), apre1 = make_uint4(0, 0, 0, 0);
    if (ar >= 0) {
        apre0 = *(const uint4*)(asrc);
        apre1 = *(const uint4*)(asrc + 8);
    }

    for (int kc = 0; kc < 20; ++kc) {
        __syncthreads();
        *(uint4*)&As[sr][sc] = apre0;
        *(uint4*)&As[sr][sc + 8] = apre1;
        __syncthreads();
        if (kc + 1 < 20) {
            int ko = (kc + 1) * 64;
            if (ar >= 0) {
                apre0 = *(const uint4*)(asrc + ko);
                apre1 = *(const uint4*)(asrc + ko + 8);
            }
        }

        int kbase = kc * 64;
        s16x8 bf0[4], bf1[4];
#pragma unroll
        for (int ci = 0; ci < 4; ++ci) {
            const u16* bp = bbase + (size_t)(ci * 16 + l15) * QWC + kbase;
            bf0[ci] = *(const s16x8*)(bp + lk);
            bf1[ci] = *(const s16x8*)(bp + 32 + lk);
        }

#pragma unroll
        for (int mi = 0; mi < 4; ++mi) {
            s16x8 af0 = *(const s16x8*)&As[mi * 16 + l15][lk];
            s16x8 af1 = *(const s16x8*)&As[mi * 16 + l15][32 + lk];
#pragma unroll
            for (int ci = 0; ci < 4; ++ci) {
                acc[mi][ci] = __builtin_amdgcn_mfma_f32_16x16x32_bf16(af0, bf0[ci], acc[mi][ci], 0, 0, 0);
                acc[mi][ci] = __builtin_amdgcn_mfma_f32_16x16x32_bf16(af1, bf1[ci], acc[mi][ci], 0, 0, 0);
            }
        }
    }

    float alpha = 1.f / (1.f + __expf(-skip[t]));
    float beta = 1.f - alpha;
#pragma unroll
    for (int mi = 0; mi < 4; ++mi) {
#pragma unroll
        for (int r = 0; r < 4; ++r) {
            int node = ridx[mi * 16 + lq * 4 + r];
            if (node < 0) continue;
#pragma unroll
            for (int ci = 0; ci < 4; ++ci) {
                size_t b0 = (size_t)node * CDIM + y * 64 + ci * 16 + l15;
                out[b0] = acc[mi][ci][r] * alpha + x[b0] * beta;
            }
        }
    }
}

// ================= gather v3: one wave per dst; single merged edge loop (sorted by et),
// 2-deep prefetch, uniform-branch segment transitions, svn in-place over qw ============
__global__ __launch_bounds__(256) void gather3_k(
    const u16* __restrict__ kb, const u16* __restrict__ vb, u16* __restrict__ qwsv,
    const float* __restrict__ pri, const int* __restrict__ rowptr, const int* __restrict__ epay,
    int N)
{
    int d = (blockIdx.x * 256 + threadIdx.x) >> 6;
    if (d >= N) return;
    int lane = threadIdx.x & 63, h = lane >> 3;
    const float rsD = 0.17677669529663687f;
    size_t rowb = (size_t)d * QWC + lane * 4;

    // preload full qw row (raw bf16; converted on segment entry)
    ushort4 qu0 = *(const ushort4*)(qwsv + rowb);
    ushort4 qu1 = *(const ushort4*)(qwsv + rowb + 256);
    ushort4 qu2 = *(const ushort4*)(qwsv + rowb + 512);
    ushort4 qu3 = *(const ushort4*)(qwsv + rowb + 768);
    ushort4 qu4 = *(const ushort4*)(qwsv + rowb + 1024);

    int p0 = __builtin_amdgcn_readfirstlane(rowptr[d * ET]);
    int p1 = __builtin_amdgcn_readfirstlane(rowptr[d * ET + ET]);

    float Sv0[4] = {0,0,0,0}, Sv1[4] = {0,0,0,0}, Sv2[4] = {0,0,0,0};
    float Sv3[4] = {0,0,0,0}, Sv4[4] = {0,0,0,0};
    float a0 = 0.f, a1 = 0.f, a2 = 0.f, a3 = 0.f, dsum = 0.f;
    int cur_et = -1;
    float cq0 = 0.f, cq1 = 0.f, cq2 = 0.f, cq3 = 0.f, cpf = 0.f;

    int payc = 0; ushort4 kuc = {0,0,0,0}, vuc = {0,0,0,0};
    if (p0 < p1) {
        payc = epay[p0];
        int s = payc & 0xFFFFFF;
        kuc = *(const ushort4*)(kb + (size_t)s * CDIM + lane * 4);
        vuc = *(const ushort4*)(vb + (size_t)s * CDIM + lane * 4);
    }

    for (int p = p0; p < p1; ++p) {
        int payn = 0; ushort4 kun = {0,0,0,0}, vun = {0,0,0,0};
        if (p + 1 < p1) {
            payn = epay[p + 1];
            int sn = payn & 0xFFFFFF;
            kun = *(const ushort4*)(kb + (size_t)sn * CDIM + lane * 4);
            vun = *(const ushort4*)(vb + (size_t)sn * CDIM + lane * 4);
        }
        int et = __builtin_amdgcn_readfirstlane(payc) >> 24;
        if (et != cur_et) {
            switch (cur_et) {   // flush finished segment (each et occurs once, '=' is correct)
                case 0: Sv0[0]=a0; Sv0[1]=a1; Sv0[2]=a2; Sv0[3]=a3; break;
                case 1: Sv1[0]=a0; Sv1[1]=a1; Sv1[2]=a2; Sv1[3]=a3; break;
                case 2: Sv2[0]=a0; Sv2[1]=a1; Sv2[2]=a2; Sv2[3]=a3; break;
                case 3: Sv3[0]=a0; Sv3[1]=a1; Sv3[2]=a2; Sv3[3]=a3; break;
                default: break;
            }
            a0 = a1 = a2 = a3 = 0.f;
            cur_et = et;
            ushort4 q = (et == 0) ? qu0 : (et == 1) ? qu1 : (et == 2) ? qu2
                       : (et == 3) ? qu3 : qu4;
            cq0 = b2f(q.x); cq1 = b2f(q.y); cq2 = b2f(q.z); cq3 = b2f(q.w);
            cpf = pri[et * HD + h] * rsD;
        }
        float t = b2f(kuc.x) * cq0 + b2f(kuc.y) * cq1 + b2f(kuc.z) * cq2 + b2f(kuc.w) * cq3;
        t += __shfl_xor(t, 1, 8);
        t += __shfl_xor(t, 2, 8);
        t += __shfl_xor(t, 4, 8);
        float ex = __expf(t * cpf);
        a0 += ex * b2f(vuc.x); a1 += ex * b2f(vuc.y);
        a2 += ex * b2f(vuc.z); a3 += ex * b2f(vuc.w);
        dsum += ex;
        payc = payn; kuc = kun; vuc = vun;
    }
    switch (cur_et) {   // final flush
        case 0: Sv0[0]=a0; Sv0[1]=a1; Sv0[2]=a2; Sv0[3]=a3; break;
        case 1: Sv1[0]=a0; Sv1[1]=a1; Sv1[2]=a2; Sv1[3]=a3; break;
        case 2: Sv2[0]=a0; Sv2[1]=a1; Sv2[2]=a2; Sv2[3]=a3; break;
        case 3: Sv3[0]=a0; Sv3[1]=a1; Sv3[2]=a2; Sv3[3]=a3; break;
        case 4: Sv4[0]=a0; Sv4[1]=a1; Sv4[2]=a2; Sv4[3]=a3; break;
        default: break;
    }

    float inv = dsum > 0.f ? 1.f / dsum : 0.f;
    ushort4 o;
    o.x=f2b(Sv0[0]*inv); o.y=f2b(Sv0[1]*inv); o.z=f2b(Sv0[2]*inv); o.w=f2b(Sv0[3]*inv);
    *(ushort4*)(qwsv + rowb) = o;
    o.x=f2b(Sv1[0]*inv); o.y=f2b(Sv1[1]*inv); o.z=f2b(Sv1[2]*inv); o.w=f2b(Sv1[3]*inv);
    *(ushort4*)(qwsv + rowb + 256) = o;
    o.x=f2b(Sv2[0]*inv); o.y=f2b(Sv2[1]*inv); o.z=f2b(Sv2[2]*inv); o.w=f2b(Sv2[3]*inv);
    *(ushort4*)(qwsv + rowb + 512) = o;
    o.x=f2b(Sv3[0]*inv); o.y=f2b(Sv3[1]*inv); o.z=f2b(Sv3[2]*inv); o.w=f2b(Sv3[3]*inv);
    *(ushort4*)(qwsv + rowb + 768) = o;
    o.x=f2b(Sv4[0]*inv); o.y=f2b(Sv4[1]*inv); o.z=f2b(Sv4[2]*inv); o.w=f2b(Sv4[3]*inv);
    *(ushort4*)(qwsv + rowb + 1024) = o;
}

// ================= launch =================
extern "C" void kernel_launch(void* const* d_in, const int* in_sizes, int n_in,
                              void* d_out, int out_size, void* d_ws, size_t ws_size,
                              hipStream_t stream) {
    const float* x    = (const float*)d_in[0];
    const float* Wk   = (const float*)d_in[1];
    const float* Wq   = (const float*)d_in[2];
    const float* Wv   = (const float*)d_in[3];
    const float* Ratt = (const float*)d_in[4];
    const float* Rmsg = (const float*)d_in[5];
    const float* pri  = (const float*)d_in[6];
    const float* Wa   = (const float*)d_in[7];
    const float* skip = (const float*)d_in[8];
    const int* src   = (const int*)d_in[9];
    const int* dst   = (const int*)d_in[10];
    const int* etype = (const int*)d_in[11];
    const int* ntype = (const int*)d_in[12];

    int N = in_sizes[12];
    int E = in_sizes[9];
    const size_t NC = (size_t)N * CDIM;
    const int KEYS = N * ET;
    const int NB = (KEYS + 255) / 256;
    const int nblk = (N + 255) / 256;
    const size_t WTE = (size_t)NT * CDIM * CDIM;       // per weight tensor (u16 elems)
    const size_t QFE = (size_t)NT * QWC * CDIM;        // folded tensors (u16 elems)

    // ---- workspace (~190 MB) ----
    u16* kb   = (u16*)d_ws;                  // NC
    u16* vb   = kb + NC;                     // NC
    u16* qwsv = vb + NC;                     // 5*NC (qw then svn, in-place)
    u16* wtb  = qwsv + 5 * NC;               // 2*WTE (Wk, Wv transposed bf16)
    u16* qf_b = wtb + 2 * WTE;               // QFE
    u16* af_b = qf_b + QFE;                  // QFE
    int* rowptr = (int*)(af_b + QFE);        // KEYS+1  (persistent)
    int* perm   = rowptr + KEYS + 1;         // N       (persistent)
    int* epay   = perm + N;                  // E       (persistent)
    int* off    = epay + E;                  // NT+1    (persistent)
    // setup-only ints aliased into qwsv (dead before the projection GEMM writes it)
    int* khist = (int*)qwsv;                 // KEYS (zeroed)
    int* kscan = khist + KEYS;               // KEYS
    int* bsum  = kscan + KEYS;               // 1024
    int* bcnt  = bsum + 1024;                // NT*nblk
    int* base  = bcnt + NT * nblk;           // NT*nblk

    hipMemsetAsync(khist, 0, (size_t)KEYS * sizeof(int), stream);

    // node buckets (atomic-free, stable)
    bhist_k<<<nblk, 256, 0, stream>>>(ntype, N, nblk, bcnt);
    bscan_k<<<1, 1024, 0, stream>>>(bcnt, base, off, NT * nblk, nblk, N);
    bscatter_k<<<nblk, 256, 0, stream>>>(ntype, N, nblk, base, perm);

    // edge counting sort by (dst, etype) -> CSR (epay packs et<<24 | src)
    ehist_k<<<(E + 255) / 256, 256, 0, stream>>>(dst, etype, E, khist);
    kscan1_k<<<NB, 256, 0, stream>>>(khist, kscan, bsum, KEYS);
    kscan2_k<<<1, 1024, 0, stream>>>(bsum, NB);
    kscan3r_k<<<NB, 256, 0, stream>>>(kscan, bsum, rowptr, KEYS, E);
    escatter_k<<<(E + 255) / 256, 256, 0, stream>>>(src, dst, etype, E, kscan, epay);

    // weight prep: Wk+Wv transpose->bf16 (one launch); folded Wq*Ratt + Rmsg*Wa (one launch)
    wconv2_k<<<dim3(4, 4, 2 * NT), 256, 0, stream>>>(Wk, Wv, wtb);
    rfold_k<<<dim3(NT * ET * HD, 2), 256, 0, stream>>>(Wq, Ratt, qf_b, Wa, Rmsg, af_b);

    int bpt = (N + 63) / 64;

    // fused k|v|qw projection (28 col-tiles fast axis; x panel read ~once)
    gemmall_k<<<dim3(28, NT * bpt), 256, 0, stream>>>(x, wtb, qf_b, kb, vb, qwsv,
                                                      perm, off, N, bpt);

    // edge gather: merged loop, prefetch; svn (normalized) in-place over qw
    gather3_k<<<(N * 64 + 255) / 256, 256, 0, stream>>>(kb, vb, qwsv, pri, rowptr, epay, N);

    // out = svn @ (Rmsg*Wa) with sigmoid-gated skip (K=1280, BK=64, direct-B)
    outgemm_k<<<NT * bpt, 256, 0, stream>>>(qwsv, af_b, (float*)d_out, perm, off, N, bpt,
                                            x, skip);
}

// Round 14
// 419.112 us; speedup vs baseline: 1.8219x; 1.0230x over previous
//
#include <hip/hip_runtime.h>
#include <math.h>

#define CDIM 256
#define HD 8
#define DD 32
#define NT 3
#define ET 5
#define QWC (ET * CDIM)     // 1280

typedef unsigned short u16;
typedef __attribute__((ext_vector_type(8))) short s16x8;
typedef __attribute__((ext_vector_type(4))) float f32x4;

__device__ __forceinline__ float b2f(u16 u) { return __uint_as_float(((unsigned)u) << 16); }
__device__ __forceinline__ u16 f2b(float x) {
    unsigned u = __float_as_uint(x);
    return (u16)((u + 0x7FFF + ((u >> 16) & 1)) >> 16);
}

// ================= node-type buckets (atomic-free, stable) =================
__global__ void bhist_k(const int* __restrict__ ntype, int N, int nblk, int* __restrict__ bcnt) {
    __shared__ int wc[4][NT];
    int b = blockIdx.x, tid = threadIdx.x, lane = tid & 63, w = tid >> 6;
    int i = b * 256 + tid;
    int t = (i < N) ? ntype[i] : -1;
#pragma unroll
    for (int r = 0; r < NT; ++r) {
        unsigned long long m = __ballot(t == r);
        if (lane == 0) wc[w][r] = __popcll(m);
    }
    __syncthreads();
    if (tid < NT) bcnt[tid * nblk + b] = wc[0][tid] + wc[1][tid] + wc[2][tid] + wc[3][tid];
}

__global__ void bscan_k(const int* __restrict__ bcnt, int* __restrict__ base,
                        int* __restrict__ off, int total, int nblk, int N) {
    __shared__ int s[1024];
    int t = threadIdx.x;
    int v = (t < total) ? bcnt[t] : 0;
    s[t] = v; __syncthreads();
    for (int o = 1; o < 1024; o <<= 1) {
        int u = (t >= o) ? s[t - o] : 0; __syncthreads();
        s[t] += u; __syncthreads();
    }
    if (t < total) base[t] = s[t] - v;
    if (t < NT) off[t] = s[t * nblk] - bcnt[t * nblk];
    if (t == NT) off[NT] = N;
}

__global__ void bscatter_k(const int* __restrict__ ntype, int N, int nblk,
                           const int* __restrict__ base, int* __restrict__ perm) {
    __shared__ int wc[4][NT];
    __shared__ int woff[4][NT];
    int b = blockIdx.x, tid = threadIdx.x, lane = tid & 63, w = tid >> 6;
    int i = b * 256 + tid;
    int t = (i < N) ? ntype[i] : -1;
    unsigned long long mlt = (1ULL << lane) - 1;
    int rank = 0;
#pragma unroll
    for (int r = 0; r < NT; ++r) {
        unsigned long long m = __ballot(t == r);
        if (lane == 0) wc[w][r] = __popcll(m);
        if (t == r) rank = __popcll(m & mlt);
    }
    __syncthreads();
    if (tid == 0) {
#pragma unroll
        for (int r = 0; r < NT; ++r) {
            int a = 0;
#pragma unroll
            for (int w0 = 0; w0 < 4; ++w0) { woff[w0][r] = a; a += wc[w0][r]; }
        }
    }
    __syncthreads();
    if (t >= 0) perm[base[t * nblk + b] + woff[w][t] + rank] = i;
}

// ================= edge counting sort by key = dst*ET + etype =================
__global__ void ehist_k(const int* __restrict__ dst, const int* __restrict__ etype, int E,
                        int* __restrict__ khist) {
    int i = blockIdx.x * 256 + threadIdx.x;
    if (i < E) atomicAdd(&khist[dst[i] * ET + etype[i]], 1);
}

__global__ void kscan1_k(const int* __restrict__ khist, int* __restrict__ kscan,
                         int* __restrict__ bsum, int KEYS) {
    __shared__ int s[256];
    int b = blockIdx.x, t = threadIdx.x, i = b * 256 + t;
    int v = (i < KEYS) ? khist[i] : 0;
    s[t] = v; __syncthreads();
    for (int o = 1; o < 256; o <<= 1) {
        int u = (t >= o) ? s[t - o] : 0; __syncthreads();
        s[t] += u; __syncthreads();
    }
    if (i < KEYS) kscan[i] = s[t] - v;
    if (t == 255) bsum[b] = s[t];
}

__global__ void kscan2_k(int* __restrict__ bsum, int NB) {
    __shared__ int s[1024];
    int t = threadIdx.x;
    int v = (t < NB) ? bsum[t] : 0;
    s[t] = v; __syncthreads();
    for (int o = 1; o < 1024; o <<= 1) {
        int u = (t >= o) ? s[t - o] : 0; __syncthreads();
        s[t] += u; __syncthreads();
    }
    if (t < NB) bsum[t] = s[t] - v;
}

// merged: kscan += bsum, and rowptr = result (+ rowptr[KEYS] = E)
__global__ void kscan3r_k(int* __restrict__ kscan, const int* __restrict__ bsum,
                          int* __restrict__ rowptr, int KEYS, int E) {
    int i = blockIdx.x * 256 + threadIdx.x;
    if (i < KEYS) {
        int v = kscan[i] + bsum[blockIdx.x];
        kscan[i] = v;
        rowptr[i] = v;
    }
    if (i == 0) rowptr[KEYS] = E;
}

// epay packs (etype << 24) | src
__global__ void escatter_k(const int* __restrict__ src, const int* __restrict__ dst,
                           const int* __restrict__ etype, int E,
                           int* __restrict__ kscan, int* __restrict__ epay) {
    int e = blockIdx.x * 256 + threadIdx.x;
    if (e < E) {
        int et = etype[e];
        int pos = atomicAdd(&kscan[dst[e] * ET + et], 1);
        epay[pos] = (et << 24) | src[e];
    }
}

// ================= fp32 -> bf16 copy (x -> xb) =================
__global__ void f2bv_k(const float* __restrict__ in, u16* __restrict__ out, size_t n4) {
    size_t i = (size_t)blockIdx.x * 256 + threadIdx.x;
    if (i >= n4) return;
    float4 v = ((const float4*)in)[i];
    ushort4 o; o.x = f2b(v.x); o.y = f2b(v.y); o.z = f2b(v.z); o.w = f2b(v.w);
    ((ushort4*)out)[i] = o;
}

// ================= Wk|Wv [t][k][c] f32 -> Wtb[z][c][k] bf16 (z: 0..NT-1 = Wk, NT..2NT-1 = Wv)
__global__ __launch_bounds__(256) void wconv2_k(const float* __restrict__ Wk,
                                                const float* __restrict__ Wv,
                                                u16* __restrict__ Wtb) {
    __shared__ u16 s[64][72];
    int k0 = blockIdx.x * 64, c0 = blockIdx.y * 64, z = blockIdx.z;
    const float* Wp = (z < NT) ? (Wk + (size_t)z * CDIM * CDIM)
                               : (Wv + (size_t)(z - NT) * CDIM * CDIM);
    int r = threadIdx.x >> 2, q = (threadIdx.x & 3) * 16;
#pragma unroll
    for (int m = 0; m < 16; m += 4) {
        float4 v = *(const float4*)(Wp + (size_t)(k0 + r) * CDIM + c0 + q + m);
        s[r][q + m + 0] = f2b(v.x); s[r][q + m + 1] = f2b(v.y);
        s[r][q + m + 2] = f2b(v.z); s[r][q + m + 3] = f2b(v.w);
    }
    __syncthreads();
    int c = threadIdx.x >> 2, kq = (threadIdx.x & 3) * 16;
    u16* op = Wtb + ((size_t)z * CDIM + c0 + c) * CDIM + k0 + kq;
#pragma unroll
    for (int m = 0; m < 16; m += 4) {
        ushort4 o;
        o.x = s[kq + m + 0][c]; o.y = s[kq + m + 1][c];
        o.z = s[kq + m + 2][c]; o.w = s[kq + m + 3][c];
        *(ushort4*)(op + m) = o;
    }
}

// ===== merged folds. y=0: qf_b[t][et*256+h*32+m][c] = sum_f Wq[t][c][h32+f]*Ratt[et,h,m,f]
//                    y=1: af_b[t][col][et*256+h*32+f] = sum_m Rmsg[et,h,f,m]*Wa[t][h32+m][col]
__global__ __launch_bounds__(256) void rfold_k(const float* __restrict__ Wq,
                                               const float* __restrict__ Ratt,
                                               u16* __restrict__ qf_b,
                                               const float* __restrict__ Wa,
                                               const float* __restrict__ Rmsg,
                                               u16* __restrict__ af_b) {
    __shared__ float Rs[DD][DD];
    int b = blockIdx.x;
    int t = b / (ET * HD);
    int eh = b % (ET * HD);
    int et = eh >> 3, h = eh & 7;
    int tid = threadIdx.x;

    if (blockIdx.y == 0) {
        float4 rv = ((const float4*)(Ratt + (size_t)eh * (DD * DD)))[tid];
        int r = tid >> 3, c4 = (tid & 7) * 4;
        Rs[r][c4 + 0] = rv.x; Rs[r][c4 + 1] = rv.y;
        Rs[r][c4 + 2] = rv.z; Rs[r][c4 + 3] = rv.w;   // Rs[m][f]
        __syncthreads();

        int c = tid;
        const float* wr = Wq + (size_t)t * (CDIM * CDIM) + (size_t)c * CDIM + h * DD;
        float wrow[DD];
#pragma unroll
        for (int f = 0; f < DD; f += 4) {
            float4 v = *(const float4*)(wr + f);
            wrow[f] = v.x; wrow[f + 1] = v.y; wrow[f + 2] = v.z; wrow[f + 3] = v.w;
        }
        for (int m = 0; m < DD; ++m) {
            float acc = 0.f;
#pragma unroll
            for (int f = 0; f < DD; ++f) acc += wrow[f] * Rs[m][f];
            qf_b[((size_t)t * QWC + et * 256 + h * 32 + m) * CDIM + c] = f2b(acc);
        }
    } else {
        float4 rv = ((const float4*)(Rmsg + (size_t)eh * (DD * DD)))[tid];
        int r = tid >> 3, c4 = (tid & 7) * 4;
        Rs[r][c4 + 0] = rv.x; Rs[r][c4 + 1] = rv.y;
        Rs[r][c4 + 2] = rv.z; Rs[r][c4 + 3] = rv.w;   // Rs[f][m]
        __syncthreads();

        int col = tid;
        float wcol[DD];
#pragma unroll
        for (int m = 0; m < DD; ++m)
            wcol[m] = Wa[(size_t)t * (CDIM * CDIM) + (size_t)(h * 32 + m) * CDIM + col];

        u16* op = af_b + ((size_t)t * CDIM + col) * QWC + et * 256 + h * 32;
        for (int f = 0; f < DD; ++f) {
            float acc = 0.f;
#pragma unroll
            for (int m = 0; m < DD; ++m) acc += Rs[f][m] * wcol[m];
            op[f] = f2b(acc);
        }
    }
}

// ================= fused projection GEMM: [k|v|qw] = xb @ {Wk,Wv,Wq*Ratt} =================
// 1D grid, XCD-grouped: all 28 col-tiles of a row-panel share bid%8 (one XCD) so the
// A-panel is fetched from HBM once and stays in that XCD's L2.
__global__ __launch_bounds__(256) void gemmall_k(
    const u16* __restrict__ xb, const u16* __restrict__ wtb, const u16* __restrict__ qf_b,
    u16* __restrict__ kb, u16* __restrict__ vb, u16* __restrict__ qwsv,
    const int* __restrict__ perm, const int* __restrict__ off, int N, int bpt, int npanel)
{
    __shared__ u16 As[64][40];
    __shared__ u16 Bs[64][40];
    __shared__ int ridx[64];

    int bid = blockIdx.x;
    int xcd = bid & 7;
    int rr_ = bid >> 3;
    int g = rr_ / 28, bx = rr_ % 28;
    int p = g * 8 + xcd;
    if (p >= npanel) return;
    int t = p / bpt, bi = p % bpt;

    int i0 = off[t] + bi * 64, iend = off[t + 1];
    if (i0 >= iend) return;
    int tid = threadIdx.x;

    u16* out; int ostr, oc0; const u16* bslab;
    const size_t CC = (size_t)CDIM * CDIM;
    if (bx < 4)      { out = kb;   ostr = CDIM; oc0 = bx * 64;       bslab = wtb + (size_t)t * CC; }
    else if (bx < 8) { out = vb;   ostr = CDIM; oc0 = (bx - 4) * 64; bslab = wtb + (size_t)(NT + t) * CC; }
    else             { out = qwsv; ostr = QWC;  oc0 = (bx - 8) * 64; bslab = qf_b + (size_t)t * QWC * CDIM; }

    if (tid < 64) ridx[tid] = (i0 + tid < iend) ? perm[i0 + tid] : -1;
    __syncthreads();

    int sr = tid >> 2, sq = (tid & 3) * 8;
    int ar = ridx[sr];
    const u16* asrc = xb + (size_t)(ar < 0 ? 0 : ar) * CDIM + sq;
    const u16* bsrc = bslab + (size_t)(oc0 + sr) * CDIM + sq;

    int lane = tid & 63, wid = tid >> 6;
    int wr = wid >> 1, wc = wid & 1;
    int l15 = lane & 15, lk = (lane >> 4) * 8;

    f32x4 acc00 = {0.f, 0.f, 0.f, 0.f}, acc01 = {0.f, 0.f, 0.f, 0.f};
    f32x4 acc10 = {0.f, 0.f, 0.f, 0.f}, acc11 = {0.f, 0.f, 0.f, 0.f};

    uint4 apre = make_uint4(0, 0, 0, 0);
    if (ar >= 0) apre = *(const uint4*)(asrc);
    uint4 bpre = *(const uint4*)(bsrc);

    for (int k0 = 0; k0 < CDIM; k0 += 32) {
        __syncthreads();
        *(uint4*)&As[sr][sq] = apre;
        *(uint4*)&Bs[sr][sq] = bpre;
        __syncthreads();

        if (k0 + 32 < CDIM) {
            if (ar >= 0) apre = *(const uint4*)(asrc + k0 + 32);
            bpre = *(const uint4*)(bsrc + k0 + 32);
        }

        s16x8 af0 = *(const s16x8*)&As[wr * 32 + l15][lk];
        s16x8 af1 = *(const s16x8*)&As[wr * 32 + 16 + l15][lk];
        s16x8 bf0 = *(const s16x8*)&Bs[wc * 32 + l15][lk];
        s16x8 bf1 = *(const s16x8*)&Bs[wc * 32 + 16 + l15][lk];

        acc00 = __builtin_amdgcn_mfma_f32_16x16x32_bf16(af0, bf0, acc00, 0, 0, 0);
        acc01 = __builtin_amdgcn_mfma_f32_16x16x32_bf16(af0, bf1, acc01, 0, 0, 0);
        acc10 = __builtin_amdgcn_mfma_f32_16x16x32_bf16(af1, bf0, acc10, 0, 0, 0);
        acc11 = __builtin_amdgcn_mfma_f32_16x16x32_bf16(af1, bf1, acc11, 0, 0, 0);
    }

    int rbase = wr * 32 + (lane >> 4) * 4;
#pragma unroll
    for (int mi = 0; mi < 2; ++mi) {
#pragma unroll
        for (int r = 0; r < 4; ++r) {
            int lrow = rbase + mi * 16 + r;
            int node = ridx[lrow];
            if (node < 0) continue;
            float v0 = (mi == 0) ? acc00[r] : acc10[r];
            float v1 = (mi == 0) ? acc01[r] : acc11[r];
            size_t b0 = (size_t)node * ostr + oc0 + wc * 32 + l15;
            out[b0]      = f2b(v0);
            out[b0 + 16] = f2b(v1);
        }
    }
}

// ================= out GEMM v3: out = svn @ af_b (K=1280) =================
__global__ __launch_bounds__(256) void outgemm_k(
    const u16* __restrict__ svn, const u16* __restrict__ af_b, float* __restrict__ out,
    const int* __restrict__ perm, const int* __restrict__ off, int N, int bpt,
    const float* __restrict__ x, const float* __restrict__ skip)
{
    __shared__ u16 As[64][68];
    __shared__ int ridx[64];

    int t = blockIdx.x / bpt, bi = blockIdx.x % bpt;
    int i0 = off[t] + bi * 64, iend = off[t + 1];
    if (i0 >= iend) return;
    int tid = threadIdx.x;
    if (tid < 64) ridx[tid] = (i0 + tid < iend) ? perm[i0 + tid] : -1;
    __syncthreads();

    int lane = tid & 63, y = tid >> 6;
    int l15 = lane & 15, lq = lane >> 4;
    int lk = lq * 8;

    int sr = tid >> 2, sc = (tid & 3) * 16;
    int ar = ridx[sr];
    const u16* asrc = svn + (size_t)(ar < 0 ? 0 : ar) * QWC + sc;
    const u16* bbase = af_b + ((size_t)t * CDIM + y * 64) * QWC;

    f32x4 acc[4][4];
#pragma unroll
    for (int mi = 0; mi < 4; ++mi)
#pragma unroll
        for (int ci = 0; ci < 4; ++ci)
            acc[mi][ci] = (f32x4){0.f, 0.f, 0.f, 0.f};

    uint4 apre0 = make_uint4(0, 0, 0, 0), apre1 = make_uint4(0, 0, 0, 0);
    if (ar >= 0) {
        apre0 = *(const uint4*)(asrc);
        apre1 = *(const uint4*)(asrc + 8);
    }

    for (int kc = 0; kc < 20; ++kc) {
        __syncthreads();
        *(uint4*)&As[sr][sc] = apre0;
        *(uint4*)&As[sr][sc + 8] = apre1;
        __syncthreads();
        if (kc + 1 < 20) {
            int ko = (kc + 1) * 64;
            if (ar >= 0) {
                apre0 = *(const uint4*)(asrc + ko);
                apre1 = *(const uint4*)(asrc + ko + 8);
            }
        }

        int kbase = kc * 64;
        s16x8 bf0[4], bf1[4];
#pragma unroll
        for (int ci = 0; ci < 4; ++ci) {
            const u16* bp = bbase + (size_t)(ci * 16 + l15) * QWC + kbase;
            bf0[ci] = *(const s16x8*)(bp + lk);
            bf1[ci] = *(const s16x8*)(bp + 32 + lk);
        }

#pragma unroll
        for (int mi = 0; mi < 4; ++mi) {
            s16x8 af0 = *(const s16x8*)&As[mi * 16 + l15][lk];
            s16x8 af1 = *(const s16x8*)&As[mi * 16 + l15][32 + lk];
#pragma unroll
            for (int ci = 0; ci < 4; ++ci) {
                acc[mi][ci] = __builtin_amdgcn_mfma_f32_16x16x32_bf16(af0, bf0[ci], acc[mi][ci], 0, 0, 0);
                acc[mi][ci] = __builtin_amdgcn_mfma_f32_16x16x32_bf16(af1, bf1[ci], acc[mi][ci], 0, 0, 0);
            }
        }
    }

    float alpha = 1.f / (1.f + __expf(-skip[t]));
    float beta = 1.f - alpha;
#pragma unroll
    for (int mi = 0; mi < 4; ++mi) {
#pragma unroll
        for (int r = 0; r < 4; ++r) {
            int node = ridx[mi * 16 + lq * 4 + r];
            if (node < 0) continue;
#pragma unroll
            for (int ci = 0; ci < 4; ++ci) {
                size_t b0 = (size_t)node * CDIM + y * 64 + ci * 16 + l15;
                out[b0] = acc[mi][ci][r] * alpha + x[b0] * beta;
            }
        }
    }
}

// ================= gather v3: one wave per dst; single merged edge loop (sorted by et),
// 2-deep prefetch, uniform-branch segment transitions, svn in-place over qw ============
__global__ __launch_bounds__(256) void gather3_k(
    const u16* __restrict__ kb, const u16* __restrict__ vb, u16* __restrict__ qwsv,
    const float* __restrict__ pri, const int* __restrict__ rowptr, const int* __restrict__ epay,
    int N)
{
    int d = (blockIdx.x * 256 + threadIdx.x) >> 6;
    if (d >= N) return;
    int lane = threadIdx.x & 63, h = lane >> 3;
    const float rsD = 0.17677669529663687f;
    size_t rowb = (size_t)d * QWC + lane * 4;

    ushort4 qu0 = *(const ushort4*)(qwsv + rowb);
    ushort4 qu1 = *(const ushort4*)(qwsv + rowb + 256);
    ushort4 qu2 = *(const ushort4*)(qwsv + rowb + 512);
    ushort4 qu3 = *(const ushort4*)(qwsv + rowb + 768);
    ushort4 qu4 = *(const ushort4*)(qwsv + rowb + 1024);

    int p0 = __builtin_amdgcn_readfirstlane(rowptr[d * ET]);
    int p1 = __builtin_amdgcn_readfirstlane(rowptr[d * ET + ET]);

    float Sv0[4] = {0,0,0,0}, Sv1[4] = {0,0,0,0}, Sv2[4] = {0,0,0,0};
    float Sv3[4] = {0,0,0,0}, Sv4[4] = {0,0,0,0};
    float a0 = 0.f, a1 = 0.f, a2 = 0.f, a3 = 0.f, dsum = 0.f;
    int cur_et = -1;
    float cq0 = 0.f, cq1 = 0.f, cq2 = 0.f, cq3 = 0.f, cpf = 0.f;

    int payc = 0; ushort4 kuc = {0,0,0,0}, vuc = {0,0,0,0};
    if (p0 < p1) {
        payc = epay[p0];
        int s = payc & 0xFFFFFF;
        kuc = *(const ushort4*)(kb + (size_t)s * CDIM + lane * 4);
        vuc = *(const ushort4*)(vb + (size_t)s * CDIM + lane * 4);
    }

    for (int p = p0; p < p1; ++p) {
        int payn = 0; ushort4 kun = {0,0,0,0}, vun = {0,0,0,0};
        if (p + 1 < p1) {
            payn = epay[p + 1];
            int sn = payn & 0xFFFFFF;
            kun = *(const ushort4*)(kb + (size_t)sn * CDIM + lane * 4);
            vun = *(const ushort4*)(vb + (size_t)sn * CDIM + lane * 4);
        }
        int et = __builtin_amdgcn_readfirstlane(payc) >> 24;
        if (et != cur_et) {
            switch (cur_et) {
                case 0: Sv0[0]=a0; Sv0[1]=a1; Sv0[2]=a2; Sv0[3]=a3; break;
                case 1: Sv1[0]=a0; Sv1[1]=a1; Sv1[2]=a2; Sv1[3]=a3; break;
                case 2: Sv2[0]=a0; Sv2[1]=a1; Sv2[2]=a2; Sv2[3]=a3; break;
                case 3: Sv3[0]=a0; Sv3[1]=a1; Sv3[2]=a2; Sv3[3]=a3; break;
                default: break;
            }
            a0 = a1 = a2 = a3 = 0.f;
            cur_et = et;
            ushort4 q = (et == 0) ? qu0 : (et == 1) ? qu1 : (et == 2) ? qu2
                       : (et == 3) ? qu3 : qu4;
            cq0 = b2f(q.x); cq1 = b2f(q.y); cq2 = b2f(q.z); cq3 = b2f(q.w);
            cpf = pri[et * HD + h] * rsD;
        }
        float t = b2f(kuc.x) * cq0 + b2f(kuc.y) * cq1 + b2f(kuc.z) * cq2 + b2f(kuc.w) * cq3;
        t += __shfl_xor(t, 1, 8);
        t += __shfl_xor(t, 2, 8);
        t += __shfl_xor(t, 4, 8);
        float ex = __expf(t * cpf);
        a0 += ex * b2f(vuc.x); a1 += ex * b2f(vuc.y);
        a2 += ex * b2f(vuc.z); a3 += ex * b2f(vuc.w);
        dsum += ex;
        payc = payn; kuc = kun; vuc = vun;
    }
    switch (cur_et) {
        case 0: Sv0[0]=a0; Sv0[1]=a1; Sv0[2]=a2; Sv0[3]=a3; break;
        case 1: Sv1[0]=a0; Sv1[1]=a1; Sv1[2]=a2; Sv1[3]=a3; break;
        case 2: Sv2[0]=a0; Sv2[1]=a1; Sv2[2]=a2; Sv2[3]=a3; break;
        case 3: Sv3[0]=a0; Sv3[1]=a1; Sv3[2]=a2; Sv3[3]=a3; break;
        case 4: Sv4[0]=a0; Sv4[1]=a1; Sv4[2]=a2; Sv4[3]=a3; break;
        default: break;
    }

    float inv = dsum > 0.f ? 1.f / dsum : 0.f;
    ushort4 o;
    o.x=f2b(Sv0[0]*inv); o.y=f2b(Sv0[1]*inv); o.z=f2b(Sv0[2]*inv); o.w=f2b(Sv0[3]*inv);
    *(ushort4*)(qwsv + rowb) = o;
    o.x=f2b(Sv1[0]*inv); o.y=f2b(Sv1[1]*inv); o.z=f2b(Sv1[2]*inv); o.w=f2b(Sv1[3]*inv);
    *(ushort4*)(qwsv + rowb + 256) = o;
    o.x=f2b(Sv2[0]*inv); o.y=f2b(Sv2[1]*inv); o.z=f2b(Sv2[2]*inv); o.w=f2b(Sv2[3]*inv);
    *(ushort4*)(qwsv + rowb + 512) = o;
    o.x=f2b(Sv3[0]*inv); o.y=f2b(Sv3[1]*inv); o.z=f2b(Sv3[2]*inv); o.w=f2b(Sv3[3]*inv);
    *(ushort4*)(qwsv + rowb + 768) = o;
    o.x=f2b(Sv4[0]*inv); o.y=f2b(Sv4[1]*inv); o.z=f2b(Sv4[2]*inv); o.w=f2b(Sv4[3]*inv);
    *(ushort4*)(qwsv + rowb + 1024) = o;
}

// ================= launch =================
extern "C" void kernel_launch(void* const* d_in, const int* in_sizes, int n_in,
                              void* d_out, int out_size, void* d_ws, size_t ws_size,
                              hipStream_t stream) {
    const float* x    = (const float*)d_in[0];
    const float* Wk   = (const float*)d_in[1];
    const float* Wq   = (const float*)d_in[2];
    const float* Wv   = (const float*)d_in[3];
    const float* Ratt = (const float*)d_in[4];
    const float* Rmsg = (const float*)d_in[5];
    const float* pri  = (const float*)d_in[6];
    const float* Wa   = (const float*)d_in[7];
    const float* skip = (const float*)d_in[8];
    const int* src   = (const int*)d_in[9];
    const int* dst   = (const int*)d_in[10];
    const int* etype = (const int*)d_in[11];
    const int* ntype = (const int*)d_in[12];

    int N = in_sizes[12];
    int E = in_sizes[9];
    const size_t NC = (size_t)N * CDIM;
    const int KEYS = N * ET;
    const int NB = (KEYS + 255) / 256;
    const int nblk = (N + 255) / 256;
    const size_t WTE = (size_t)NT * CDIM * CDIM;       // per weight tensor (u16 elems)
    const size_t QFE = (size_t)NT * QWC * CDIM;        // folded tensors (u16 elems)

    // ---- workspace (~190 MB) ----
    u16* kb   = (u16*)d_ws;                  // NC
    u16* vb   = kb + NC;                     // NC
    u16* qwsv = vb + NC;                     // 5*NC (qw then svn, in-place)
    u16* wtb  = qwsv + 5 * NC;               // 2*WTE (Wk, Wv transposed bf16)
    u16* qf_b = wtb + 2 * WTE;               // QFE
    u16* af_b = qf_b + QFE;                  // QFE
    int* rowptr = (int*)(af_b + QFE);        // KEYS+1  (persistent)
    int* perm   = rowptr + KEYS + 1;         // N       (persistent)
    int* epay   = perm + N;                  // E       (persistent)
    int* off    = epay + E;                  // NT+1    (persistent)
    // setup-only ints aliased into qwsv (dead before the projection GEMM writes it)
    int* khist = (int*)qwsv;                 // KEYS (zeroed)
    int* kscan = khist + KEYS;               // KEYS
    int* bsum  = kscan + KEYS;               // 1024
    int* bcnt  = bsum + 1024;                // NT*nblk
    int* base  = bcnt + NT * nblk;           // NT*nblk

    // xb (bf16 copy of x) lives in d_out scratch: NC u16 = half of out bytes;
    // fully dead before outgemm_k overwrites d_out.
    u16* xb = (u16*)d_out;

    hipMemsetAsync(khist, 0, (size_t)KEYS * sizeof(int), stream);

    // node buckets (atomic-free, stable)
    bhist_k<<<nblk, 256, 0, stream>>>(ntype, N, nblk, bcnt);
    bscan_k<<<1, 1024, 0, stream>>>(bcnt, base, off, NT * nblk, nblk, N);
    bscatter_k<<<nblk, 256, 0, stream>>>(ntype, N, nblk, base, perm);

    // edge counting sort by (dst, etype) -> CSR (epay packs et<<24 | src)
    ehist_k<<<(E + 255) / 256, 256, 0, stream>>>(dst, etype, E, khist);
    kscan1_k<<<NB, 256, 0, stream>>>(khist, kscan, bsum, KEYS);
    kscan2_k<<<1, 1024, 0, stream>>>(bsum, NB);
    kscan3r_k<<<NB, 256, 0, stream>>>(kscan, bsum, rowptr, KEYS, E);
    escatter_k<<<(E + 255) / 256, 256, 0, stream>>>(src, dst, etype, E, kscan, epay);

    // weight prep + x -> bf16
    wconv2_k<<<dim3(4, 4, 2 * NT), 256, 0, stream>>>(Wk, Wv, wtb);
    rfold_k<<<dim3(NT * ET * HD, 2), 256, 0, stream>>>(Wq, Ratt, qf_b, Wa, Rmsg, af_b);
    size_t n4 = NC / 4;
    f2bv_k<<<(int)((n4 + 255) / 256), 256, 0, stream>>>(x, xb, n4);

    int bpt = (N + 63) / 64;
    int npanel = NT * bpt;
    int ppad = (npanel + 7) & ~7;

    // fused k|v|qw projection, XCD-grouped 1D grid (panel's 28 col-tiles on one XCD)
    gemmall_k<<<ppad * 28, 256, 0, stream>>>(xb, wtb, qf_b, kb, vb, qwsv,
                                             perm, off, N, bpt, npanel);

    // edge gather: merged loop, prefetch; svn (normalized) in-place over qw
    gather3_k<<<(N * 64 + 255) / 256, 256, 0, stream>>>(kb, vb, qwsv, pri, rowptr, epay, N);

    // out = svn @ (Rmsg*Wa) with sigmoid-gated skip (K=1280, BK=64, direct-B)
    outgemm_k<<<NT * bpt, 256, 0, stream>>>(qwsv, af_b, (float*)d_out, perm, off, N, bpt,
                                            x, skip);
}